// Round 1
// baseline (1220.587 us; speedup 1.0000x reference)
//
#include <hip/hip_runtime.h>
#include <hip/hip_bf16.h>

// Problem: B=4, S=2048, D=1024, H=16, DH=64. M = B*S = 8192.
// Pipeline: LN -> Qproj(bf16 mfma) -> KVproj(bf16 mfma) -> flash attn (fp32)
//           -> out proj + bias + skip (fp32 out)

#define Bn 4
#define Sn 2048
#define Dn 1024
#define Hn 16
#define DHn 64
#define Mn (Bn*Sn)

typedef short short8 __attribute__((ext_vector_type(8)));
typedef unsigned short ushort8 __attribute__((ext_vector_type(8)));
typedef unsigned short ushort4v __attribute__((ext_vector_type(4)));
typedef float f32x4 __attribute__((ext_vector_type(4)));

__device__ inline float bf2f(unsigned short u) {
    union { unsigned int i; float f; } c;
    c.i = ((unsigned int)u) << 16;
    return c.f;
}

__device__ inline unsigned short f2bf(float f) {
    union { float f; unsigned int i; } c;
    c.f = f;
    unsigned int i = c.i;
    unsigned int lsb = (i >> 16) & 1;
    i += 0x7fffu + lsb;   // round-to-nearest-even
    return (unsigned short)(i >> 16);
}

// ---------------- fp32 -> bf16 elementwise ----------------
__global__ __launch_bounds__(256) void f2bf_kernel(const float* __restrict__ in,
                                                   unsigned short* __restrict__ out,
                                                   int n4) {
    int i = blockIdx.x * 256 + threadIdx.x;
    if (i < n4) {
        float4 v = *(const float4*)(in + (size_t)i * 4);
        ushort4v r;
        r.x = f2bf(v.x); r.y = f2bf(v.y); r.z = f2bf(v.z); r.w = f2bf(v.w);
        *(ushort4v*)(out + (size_t)i * 4) = r;
    }
}

// ---------------- LayerNorm: fp32 in -> bf16 out ----------------
__global__ __launch_bounds__(256) void ln_kernel(const float* __restrict__ x,
                                                 const float* __restrict__ g,
                                                 const float* __restrict__ bta,
                                                 unsigned short* __restrict__ xn) {
    int row = blockIdx.x;
    int t = threadIdx.x;
    const float* xr = x + (size_t)row * Dn;
    float4 v = *(const float4*)(xr + t * 4);
    float s = v.x + v.y + v.z + v.w;
    float sq = v.x * v.x + v.y * v.y + v.z * v.z + v.w * v.w;
    for (int off = 32; off; off >>= 1) {
        s += __shfl_down(s, off);
        sq += __shfl_down(sq, off);
    }
    __shared__ float ss[4], ssq[4];
    int wave = t >> 6, lane = t & 63;
    if (lane == 0) { ss[wave] = s; ssq[wave] = sq; }
    __syncthreads();
    float tot = ss[0] + ss[1] + ss[2] + ss[3];
    float totq = ssq[0] + ssq[1] + ssq[2] + ssq[3];
    float mean = tot * (1.0f / Dn);
    float var = totq * (1.0f / Dn) - mean * mean;
    float rstd = rsqrtf(var + 1e-5f);
    float4 gv = *(const float4*)(g + t * 4);
    float4 bv = *(const float4*)(bta + t * 4);
    ushort4v r;
    r.x = f2bf((v.x - mean) * rstd * gv.x + bv.x);
    r.y = f2bf((v.y - mean) * rstd * gv.y + bv.y);
    r.z = f2bf((v.z - mean) * rstd * gv.z + bv.z);
    r.w = f2bf((v.w - mean) * rstd * gv.w + bv.w);
    *(ushort4v*)(xn + (size_t)row * Dn + t * 4) = r;
}

// ---------------- bf16 BT-GEMM: C = A(MxK) * Bw(NxK)^T + bias ----------------
// 128x128 tile, 256 threads = 4 waves (2x2), each wave 4x4 tiles of 16x16x32 MFMA.
// A/B fragment: lane holds row (lane&15), k = (lane>>4)*8 + j  (8 contiguous bf16).
// C/D: col = lane&15, row = (lane>>4)*4 + reg.
template <bool ADD_SKIP, bool OUT_BF16>
__global__ __launch_bounds__(256, 2) void gemm_bt(const unsigned short* __restrict__ A,
                                                  const unsigned short* __restrict__ Bw,
                                                  const float* __restrict__ bias,
                                                  const float* __restrict__ skip,
                                                  void* __restrict__ Cout,
                                                  int M, int N, int K) {
    __shared__ unsigned short As[128 * 32];
    __shared__ unsigned short Bs[128 * 32];
    const int tid = threadIdx.x;
    const int wave = tid >> 6, lane = tid & 63;
    const int warp_m = wave & 1, warp_n = wave >> 1;
    const int bm = blockIdx.x, bn = blockIdx.y;
    const int l4 = lane & 3, lr = lane >> 2;   // staging: col-group, row-in-16
    const int quad = lane >> 4, r16 = lane & 15;

    f32x4 acc[4][4];
#pragma unroll
    for (int i = 0; i < 4; i++)
#pragma unroll
        for (int j = 0; j < 4; j++) acc[i][j] = (f32x4){0.f, 0.f, 0.f, 0.f};

    for (int k0 = 0; k0 < K; k0 += 32) {
        // stage 128x32 A and B tiles; inst = wave + 4*i covers 16 rows each
        ushort8 ar[2], br[2];
#pragma unroll
        for (int i = 0; i < 2; ++i) {
            int inst = wave + 4 * i;
            int row = inst * 16 + lr;
            ar[i] = *(const ushort8*)(A + (size_t)(bm * 128 + row) * K + k0 + l4 * 8);
            br[i] = *(const ushort8*)(Bw + (size_t)(bn * 128 + row) * K + k0 + l4 * 8);
        }
        __syncthreads();   // previous iter's readers done
#pragma unroll
        for (int i = 0; i < 2; ++i) {
            int inst = wave + 4 * i;
            *(ushort8*)(As + inst * 512 + lane * 8) = ar[i];
            *(ushort8*)(Bs + inst * 512 + lane * 8) = br[i];
        }
        __syncthreads();

        short8 afr[4], bfr[4];
#pragma unroll
        for (int i = 0; i < 4; ++i) {
            int row = warp_m * 64 + i * 16 + r16;
            afr[i] = *(const short8*)(As + row * 32 + quad * 8);
        }
#pragma unroll
        for (int j = 0; j < 4; ++j) {
            int row = warp_n * 64 + j * 16 + r16;
            bfr[j] = *(const short8*)(Bs + row * 32 + quad * 8);
        }
#pragma unroll
        for (int i = 0; i < 4; ++i)
#pragma unroll
            for (int j = 0; j < 4; ++j)
                acc[i][j] = __builtin_amdgcn_mfma_f32_16x16x32_bf16(afr[i], bfr[j], acc[i][j], 0, 0, 0);
    }

    // epilogue
#pragma unroll
    for (int j = 0; j < 4; ++j) {
        int gcol = bn * 128 + warp_n * 64 + j * 16 + r16;
        float bv = bias[gcol];
#pragma unroll
        for (int i = 0; i < 4; ++i) {
#pragma unroll
            for (int r = 0; r < 4; ++r) {
                int grow = bm * 128 + warp_m * 64 + i * 16 + quad * 4 + r;
                float v = acc[i][j][r] + bv;
                size_t idx = (size_t)grow * N + gcol;
                if (ADD_SKIP) v += skip[idx];
                if (OUT_BF16)
                    ((unsigned short*)Cout)[idx] = f2bf(v);
                else
                    ((float*)Cout)[idx] = v;
            }
        }
    }
}

// ---------------- flash attention (fp32 compute, bf16 in/out) ----------------
// grid: (S/64, H, B); 256 threads; thread (qr = t>>2, qtr = t&3) owns
// q-row qr's DH quarter [qtr*16, qtr*16+16).
__global__ __launch_bounds__(256, 2) void attn_kernel(const unsigned short* __restrict__ Q,
                                                      const unsigned short* __restrict__ KV,
                                                      const int* __restrict__ lens,
                                                      unsigned short* __restrict__ Ctx) {
    const int qt = blockIdx.x, h = blockIdx.y, b = blockIdx.z;
    const int tid = threadIdx.x;
    const int qr = tid >> 2, qtr = tid & 3;
    const int len = lens[b];
    const int qp = qt * 64 + qr;

    __shared__ float Ks[64][68];
    __shared__ float Vs[64][68];

    // load this thread's q quarter, pre-scaled by 1/sqrt(DH)
    float q[16];
    {
        const unsigned short* qptr = Q + ((size_t)(b * Sn + qp)) * Dn + h * 64 + qtr * 16;
#pragma unroll
        for (int jj = 0; jj < 16; jj += 8) {
            ushort8 u = *(const ushort8*)(qptr + jj);
#pragma unroll
            for (int e = 0; e < 8; e++) q[jj + e] = bf2f(u[e]) * 0.125f;
        }
    }

    float o[16];
#pragma unroll
    for (int j = 0; j < 16; j++) o[j] = 0.f;
    float m = -1e30f, l = 0.f;

    const int ktend = min(qt, (len - 1) >> 6);
    for (int kt = 0; kt <= ktend; ++kt) {
        __syncthreads();
        // stage K,V tile (64x64) as fp32 into LDS
        {
            int r = tid >> 2;
            size_t base = ((size_t)(b * Sn + kt * 64 + r)) * (2 * Dn) + h * 64 + qtr * 16;
            const unsigned short* kp_ = KV + base;
            const unsigned short* vp_ = KV + base + Dn;
#pragma unroll
            for (int jj = 0; jj < 16; jj += 8) {
                ushort8 ku = *(const ushort8*)(kp_ + jj);
                ushort8 vu = *(const ushort8*)(vp_ + jj);
                float4 ka, kb, va, vb;
                ka.x = bf2f(ku[0]); ka.y = bf2f(ku[1]); ka.z = bf2f(ku[2]); ka.w = bf2f(ku[3]);
                kb.x = bf2f(ku[4]); kb.y = bf2f(ku[5]); kb.z = bf2f(ku[6]); kb.w = bf2f(ku[7]);
                va.x = bf2f(vu[0]); va.y = bf2f(vu[1]); va.z = bf2f(vu[2]); va.w = bf2f(vu[3]);
                vb.x = bf2f(vu[4]); vb.y = bf2f(vu[5]); vb.z = bf2f(vu[6]); vb.w = bf2f(vu[7]);
                *(float4*)&Ks[r][qtr * 16 + jj] = ka;
                *(float4*)&Ks[r][qtr * 16 + jj + 4] = kb;
                *(float4*)&Vs[r][qtr * 16 + jj] = va;
                *(float4*)&Vs[r][qtr * 16 + jj + 4] = vb;
            }
        }
        __syncthreads();

        // partial scores over this thread's 16 dims, reduced across the 4 qtr lanes
        float s[64];
        const int kbase = kt * 64;
#pragma unroll
        for (int kk = 0; kk < 64; ++kk) {
            const float4* kr = (const float4*)&Ks[kk][qtr * 16];
            float4 k0 = kr[0], k1 = kr[1], k2 = kr[2], k3 = kr[3];
            float a0 = q[0] * k0.x + q[1] * k0.y + q[2] * k0.z + q[3] * k0.w;
            float a1 = q[4] * k1.x + q[5] * k1.y + q[6] * k1.z + q[7] * k1.w;
            float a2 = q[8] * k2.x + q[9] * k2.y + q[10] * k2.z + q[11] * k2.w;
            float a3 = q[12] * k3.x + q[13] * k3.y + q[14] * k3.z + q[15] * k3.w;
            float acc = (a0 + a1) + (a2 + a3);
            acc += __shfl_xor(acc, 1);
            acc += __shfl_xor(acc, 2);
            int kp = kbase + kk;
            bool valid = (kp <= qp) && (kp < len);
            s[kk] = valid ? acc : -1e30f;
        }
        float mt = s[0];
#pragma unroll
        for (int kk = 1; kk < 64; ++kk) mt = fmaxf(mt, s[kk]);
        float mnew = fmaxf(m, mt);
        float alpha = __expf(m - mnew);
        l *= alpha;
#pragma unroll
        for (int j = 0; j < 16; j++) o[j] *= alpha;
#pragma unroll
        for (int kk = 0; kk < 64; ++kk) {
            float p = __expf(s[kk] - mnew);
            l += p;
            const float4* vr = (const float4*)&Vs[kk][qtr * 16];
            float4 v0 = vr[0], v1 = vr[1], v2 = vr[2], v3 = vr[3];
            o[0] += p * v0.x; o[1] += p * v0.y; o[2] += p * v0.z; o[3] += p * v0.w;
            o[4] += p * v1.x; o[5] += p * v1.y; o[6] += p * v1.z; o[7] += p * v1.w;
            o[8] += p * v2.x; o[9] += p * v2.y; o[10] += p * v2.z; o[11] += p * v2.w;
            o[12] += p * v3.x; o[13] += p * v3.y; o[14] += p * v3.z; o[15] += p * v3.w;
        }
        m = mnew;
    }

    float inv = 1.0f / l;
    unsigned short* co = Ctx + ((size_t)(b * Sn + qp)) * Dn + h * 64 + qtr * 16;
#pragma unroll
    for (int jj = 0; jj < 16; jj += 4) {
        ushort4v r;
        r.x = f2bf(o[jj + 0] * inv);
        r.y = f2bf(o[jj + 1] * inv);
        r.z = f2bf(o[jj + 2] * inv);
        r.w = f2bf(o[jj + 3] * inv);
        *(ushort4v*)(co + jj) = r;
    }
}

// ---------------- launcher ----------------
extern "C" void kernel_launch(void* const* d_in, const int* in_sizes, int n_in,
                              void* d_out, int out_size, void* d_ws, size_t ws_size,
                              hipStream_t stream) {
    const float* x = (const float*)d_in[0];
    const int* lens = (const int*)d_in[1];
    const float* Wq = (const float*)d_in[2];
    const float* bq = (const float*)d_in[3];
    const float* Wkv = (const float*)d_in[4];
    const float* bkv = (const float*)d_in[5];
    const float* Wo = (const float*)d_in[6];
    const float* bo = (const float*)d_in[7];
    const float* ln_g = (const float*)d_in[8];
    const float* ln_b = (const float*)d_in[9];
    float* out = (float*)d_out;

    // workspace layout (bytes)
    char* ws = (char*)d_ws;
    unsigned short* xn_bf = (unsigned short*)ws;                 // M*D*2      = 16 MB
    unsigned short* wq_bf = (unsigned short*)(ws + (size_t)16 * 1024 * 1024);   // 2 MB
    unsigned short* wkv_bf = (unsigned short*)(ws + (size_t)18 * 1024 * 1024);  // 4 MB
    unsigned short* wo_bf = (unsigned short*)(ws + (size_t)22 * 1024 * 1024);   // 2 MB
    unsigned short* q_bf = (unsigned short*)(ws + (size_t)24 * 1024 * 1024);    // 16 MB
    unsigned short* kv_bf = (unsigned short*)(ws + (size_t)40 * 1024 * 1024);   // 32 MB
    unsigned short* ctx_bf = (unsigned short*)(ws + (size_t)72 * 1024 * 1024);  // 16 MB
    // total 88 MB

    // 1. weight fp32 -> bf16
    f2bf_kernel<<<(Dn * Dn / 4 + 255) / 256, 256, 0, stream>>>(Wq, wq_bf, Dn * Dn / 4);
    f2bf_kernel<<<(2 * Dn * Dn / 4 + 255) / 256, 256, 0, stream>>>(Wkv, wkv_bf, 2 * Dn * Dn / 4);
    f2bf_kernel<<<(Dn * Dn / 4 + 255) / 256, 256, 0, stream>>>(Wo, wo_bf, Dn * Dn / 4);

    // 2. LayerNorm -> bf16 xn
    ln_kernel<<<Mn, 256, 0, stream>>>(x, ln_g, ln_b, xn_bf);

    // 3. Q = xn @ Wq^T + bq   (bf16 out)
    {
        dim3 grid(Mn / 128, Dn / 128);
        gemm_bt<false, true><<<grid, 256, 0, stream>>>(xn_bf, wq_bf, bq, nullptr,
                                                       (void*)q_bf, Mn, Dn, Dn);
    }
    // 4. KV = xn @ Wkv^T + bkv   (bf16 out)
    {
        dim3 grid(Mn / 128, 2 * Dn / 128);
        gemm_bt<false, true><<<grid, 256, 0, stream>>>(xn_bf, wkv_bf, bkv, nullptr,
                                                       (void*)kv_bf, Mn, 2 * Dn, Dn);
    }
    // 5. attention -> ctx bf16
    {
        dim3 grid(Sn / 64, Hn, Bn);
        attn_kernel<<<grid, 256, 0, stream>>>(q_bf, kv_bf, lens, ctx_bf);
    }
    // 6. out = ctx @ Wo^T + bo + x   (fp32 out)
    {
        dim3 grid(Mn / 128, Dn / 128);
        gemm_bt<true, false><<<grid, 256, 0, stream>>>(ctx_bf, wo_bf, bo, x,
                                                       (void*)out, Mn, Dn, Dn);
    }
}

// Round 2
// 324.284 us; speedup vs baseline: 3.7639x; 3.7639x over previous
//
#include <hip/hip_runtime.h>
#include <hip/hip_bf16.h>

// Problem: B=4, S=2048, D=1024, H=16, DH=64. M = B*S = 8192.
// Pipeline: LN -> Qproj(bf16 mfma) -> KVproj(bf16 mfma) -> flash attn (bf16 MFMA)
//           -> out proj + bias + skip (fp32 out)

#define Bn 4
#define Sn 2048
#define Dn 1024
#define Hn 16
#define DHn 64
#define Mn (Bn*Sn)

typedef short short8 __attribute__((ext_vector_type(8)));
typedef unsigned short ushort8 __attribute__((ext_vector_type(8)));
typedef unsigned short ushort4v __attribute__((ext_vector_type(4)));
typedef float f32x4 __attribute__((ext_vector_type(4)));

__device__ inline float bf2f(unsigned short u) {
    union { unsigned int i; float f; } c;
    c.i = ((unsigned int)u) << 16;
    return c.f;
}

__device__ inline unsigned short f2bf(float f) {
    union { float f; unsigned int i; } c;
    c.f = f;
    unsigned int i = c.i;
    unsigned int lsb = (i >> 16) & 1;
    i += 0x7fffu + lsb;   // round-to-nearest-even
    return (unsigned short)(i >> 16);
}

// truncating fp32->bf16 (fine for p in [0,1]; saves the RNE sequence)
__device__ inline unsigned short f2bf_t(float f) {
    union { float f; unsigned int i; } c;
    c.f = f;
    return (unsigned short)(c.i >> 16);
}

// ---------------- fp32 -> bf16 elementwise ----------------
__global__ __launch_bounds__(256) void f2bf_kernel(const float* __restrict__ in,
                                                   unsigned short* __restrict__ out,
                                                   int n4) {
    int i = blockIdx.x * 256 + threadIdx.x;
    if (i < n4) {
        float4 v = *(const float4*)(in + (size_t)i * 4);
        ushort4v r;
        r.x = f2bf(v.x); r.y = f2bf(v.y); r.z = f2bf(v.z); r.w = f2bf(v.w);
        *(ushort4v*)(out + (size_t)i * 4) = r;
    }
}

// ---------------- LayerNorm: fp32 in -> bf16 out ----------------
__global__ __launch_bounds__(256) void ln_kernel(const float* __restrict__ x,
                                                 const float* __restrict__ g,
                                                 const float* __restrict__ bta,
                                                 unsigned short* __restrict__ xn) {
    int row = blockIdx.x;
    int t = threadIdx.x;
    const float* xr = x + (size_t)row * Dn;
    float4 v = *(const float4*)(xr + t * 4);
    float s = v.x + v.y + v.z + v.w;
    float sq = v.x * v.x + v.y * v.y + v.z * v.z + v.w * v.w;
    for (int off = 32; off; off >>= 1) {
        s += __shfl_down(s, off);
        sq += __shfl_down(sq, off);
    }
    __shared__ float ss[4], ssq[4];
    int wave = t >> 6, lane = t & 63;
    if (lane == 0) { ss[wave] = s; ssq[wave] = sq; }
    __syncthreads();
    float tot = ss[0] + ss[1] + ss[2] + ss[3];
    float totq = ssq[0] + ssq[1] + ssq[2] + ssq[3];
    float mean = tot * (1.0f / Dn);
    float var = totq * (1.0f / Dn) - mean * mean;
    float rstd = rsqrtf(var + 1e-5f);
    float4 gv = *(const float4*)(g + t * 4);
    float4 bv = *(const float4*)(bta + t * 4);
    ushort4v r;
    r.x = f2bf((v.x - mean) * rstd * gv.x + bv.x);
    r.y = f2bf((v.y - mean) * rstd * gv.y + bv.y);
    r.z = f2bf((v.z - mean) * rstd * gv.z + bv.z);
    r.w = f2bf((v.w - mean) * rstd * gv.w + bv.w);
    *(ushort4v*)(xn + (size_t)row * Dn + t * 4) = r;
}

// ---------------- bf16 BT-GEMM: C = A(MxK) * Bw(NxK)^T + bias ----------------
// (unchanged from round 1 — known-passing; GEMM gets its own round next)
template <bool ADD_SKIP, bool OUT_BF16>
__global__ __launch_bounds__(256, 2) void gemm_bt(const unsigned short* __restrict__ A,
                                                  const unsigned short* __restrict__ Bw,
                                                  const float* __restrict__ bias,
                                                  const float* __restrict__ skip,
                                                  void* __restrict__ Cout,
                                                  int M, int N, int K) {
    __shared__ unsigned short As[128 * 32];
    __shared__ unsigned short Bs[128 * 32];
    const int tid = threadIdx.x;
    const int wave = tid >> 6, lane = tid & 63;
    const int warp_m = wave & 1, warp_n = wave >> 1;
    const int bm = blockIdx.x, bn = blockIdx.y;
    const int l4 = lane & 3, lr = lane >> 2;
    const int quad = lane >> 4, r16 = lane & 15;

    f32x4 acc[4][4];
#pragma unroll
    for (int i = 0; i < 4; i++)
#pragma unroll
        for (int j = 0; j < 4; j++) acc[i][j] = (f32x4){0.f, 0.f, 0.f, 0.f};

    for (int k0 = 0; k0 < K; k0 += 32) {
        ushort8 ar[2], br[2];
#pragma unroll
        for (int i = 0; i < 2; ++i) {
            int inst = wave + 4 * i;
            int row = inst * 16 + lr;
            ar[i] = *(const ushort8*)(A + (size_t)(bm * 128 + row) * K + k0 + l4 * 8);
            br[i] = *(const ushort8*)(Bw + (size_t)(bn * 128 + row) * K + k0 + l4 * 8);
        }
        __syncthreads();
#pragma unroll
        for (int i = 0; i < 2; ++i) {
            int inst = wave + 4 * i;
            *(ushort8*)(As + inst * 512 + lane * 8) = ar[i];
            *(ushort8*)(Bs + inst * 512 + lane * 8) = br[i];
        }
        __syncthreads();

        short8 afr[4], bfr[4];
#pragma unroll
        for (int i = 0; i < 4; ++i) {
            int row = warp_m * 64 + i * 16 + r16;
            afr[i] = *(const short8*)(As + row * 32 + quad * 8);
        }
#pragma unroll
        for (int j = 0; j < 4; ++j) {
            int row = warp_n * 64 + j * 16 + r16;
            bfr[j] = *(const short8*)(Bs + row * 32 + quad * 8);
        }
#pragma unroll
        for (int i = 0; i < 4; ++i)
#pragma unroll
            for (int j = 0; j < 4; ++j)
                acc[i][j] = __builtin_amdgcn_mfma_f32_16x16x32_bf16(afr[i], bfr[j], acc[i][j], 0, 0, 0);
    }

#pragma unroll
    for (int j = 0; j < 4; ++j) {
        int gcol = bn * 128 + warp_n * 64 + j * 16 + r16;
        float bv = bias[gcol];
#pragma unroll
        for (int i = 0; i < 4; ++i) {
#pragma unroll
            for (int r = 0; r < 4; ++r) {
                int grow = bm * 128 + warp_m * 64 + i * 16 + quad * 4 + r;
                float v = acc[i][j][r] + bv;
                size_t idx = (size_t)grow * N + gcol;
                if (ADD_SKIP) v += skip[idx];
                if (OUT_BF16)
                    ((unsigned short*)Cout)[idx] = f2bf(v);
                else
                    ((float*)Cout)[idx] = v;
            }
        }
    }
}

// ---------------- MFMA flash attention ----------------
// grid (S/64, H, B), 256 threads = 4 waves; wave w handles q rows [qt*64+w*16, +16).
// Per k-tile (64 keys):
//   S^T = K·Q^T  (A = K rows, B = Q rows, 16x16x32 bf16, 4 m-tiles x 2 k-steps)
//     -> C layout: lane holds col q = lane&15, rows k = mt*16 + quad*4 + reg
//   softmax per-q: lane-local over 16 vals + shfl_xor(16,32) across quads
//   P -> per-wave private LDS tile (A-operand relayout), V staged transposed
//   O += P·V  (A = P rows(q), B = Vt rows(dh)), accum in C layout.
#define ATT_ST 72   // LDS row stride in ushorts (144B: 16B-aligned, bank-spread)

__global__ __launch_bounds__(256, 2) void attn_kernel(const unsigned short* __restrict__ Q,
                                                      const unsigned short* __restrict__ KV,
                                                      const int* __restrict__ lens,
                                                      unsigned short* __restrict__ Ctx) {
    const int qt = blockIdx.x, h = blockIdx.y, b = blockIdx.z;
    const int tid = threadIdx.x;
    const int wave = tid >> 6, lane = tid & 63;
    const int quad = lane >> 4, c = lane & 15;
    const int len = lens[b];
    const int qw = qt * 64 + wave * 16;   // wave's q base
    const int myq = qw + c;               // this lane's softmax q

    __shared__ unsigned short Ks[64 * ATT_ST];
    __shared__ unsigned short Vt[64 * ATT_ST];
    __shared__ unsigned short Ps[4][16 * ATT_ST];

    // Q fragments (B-operand: lane holds row q = c, d = ks*32 + quad*8 .. +7)
    short8 qfrag[2];
    {
        const unsigned short* qp = Q + ((size_t)(b * Sn + qw + c)) * Dn + h * 64 + quad * 8;
        qfrag[0] = *(const short8*)(qp);
        qfrag[1] = *(const short8*)(qp + 32);
    }

    f32x4 acc_o[4];   // [dhtile]; lane holds rows q = quad*4+reg, col dh = dhtile*16+c
#pragma unroll
    for (int j = 0; j < 4; j++) acc_o[j] = (f32x4){0.f, 0.f, 0.f, 0.f};
    float m_run = -1e30f;
    float l_run = 0.f;    // partial over this lane's k subset (reduced across quads at end)

    const int ktend = min(qt, (len - 1) >> 6);
    for (int kt = 0; kt <= ktend; ++kt) {
        __syncthreads();   // prior iteration's K/Vt readers done
        // ---- stage K tile [krow][d] ----
        {
            const int krow = tid >> 2, dp = tid & 3;
            const unsigned short* kp = KV + ((size_t)(b * Sn + kt * 64 + krow)) * (2 * Dn) + h * 64 + dp * 16;
            ushort8 k0v = *(const ushort8*)(kp);
            ushort8 k1v = *(const ushort8*)(kp + 8);
            *(ushort8*)(&Ks[krow * ATT_ST + dp * 16]) = k0v;
            *(ushort8*)(&Ks[krow * ATT_ST + dp * 16 + 8]) = k1v;
        }
        // ---- stage V transposed: Vt[d][krow] ----
        {
            const int kg = tid >> 4, dg = tid & 15;   // k base kg*4, d base dg*4
            const unsigned short* vp = KV + ((size_t)(b * Sn + kt * 64 + kg * 4)) * (2 * Dn) + Dn + h * 64 + dg * 4;
            ushort4v r0 = *(const ushort4v*)(vp);
            ushort4v r1 = *(const ushort4v*)(vp + 2 * Dn);
            ushort4v r2 = *(const ushort4v*)(vp + 4 * Dn);
            ushort4v r3 = *(const ushort4v*)(vp + 6 * Dn);
#pragma unroll
            for (int w = 0; w < 4; ++w) {
                ushort4v t;
                t.x = r0[w]; t.y = r1[w]; t.z = r2[w]; t.w = r3[w];
                *(ushort4v*)(&Vt[(dg * 4 + w) * ATT_ST + kg * 4]) = t;
            }
        }
        __syncthreads();

        // ---- S^T = K·Q^T ----
        f32x4 sacc[4];
#pragma unroll
        for (int mt = 0; mt < 4; ++mt) sacc[mt] = (f32x4){0.f, 0.f, 0.f, 0.f};
#pragma unroll
        for (int mt = 0; mt < 4; ++mt) {
            short8 kf0 = *(const short8*)(&Ks[(mt * 16 + c) * ATT_ST + quad * 8]);
            short8 kf1 = *(const short8*)(&Ks[(mt * 16 + c) * ATT_ST + 32 + quad * 8]);
            sacc[mt] = __builtin_amdgcn_mfma_f32_16x16x32_bf16(kf0, qfrag[0], sacc[mt], 0, 0, 0);
            sacc[mt] = __builtin_amdgcn_mfma_f32_16x16x32_bf16(kf1, qfrag[1], sacc[mt], 0, 0, 0);
        }

        // ---- mask + scale + per-q max ----
        float sv[16];
        float mloc = -1e30f;
        const int kb = kt * 64;
#pragma unroll
        for (int mt = 0; mt < 4; ++mt) {
#pragma unroll
            for (int r = 0; r < 4; ++r) {
                int kpos = kb + mt * 16 + quad * 4 + r;
                bool valid = (kpos <= myq) && (kpos < len);
                float v = valid ? sacc[mt][r] * 0.125f : -1e30f;
                sv[mt * 4 + r] = v;
                mloc = fmaxf(mloc, v);
            }
        }
        mloc = fmaxf(mloc, __shfl_xor(mloc, 16));
        mloc = fmaxf(mloc, __shfl_xor(mloc, 32));
        float mnew = fmaxf(m_run, mloc);
        float alpha = __expf(m_run - mnew);
        m_run = mnew;
        l_run *= alpha;

        // rescale O (alpha indexed by q=c; O rows are q = quad*4+r)
        float ar_[4];
#pragma unroll
        for (int r = 0; r < 4; ++r) ar_[r] = __shfl(alpha, quad * 4 + r);
#pragma unroll
        for (int j = 0; j < 4; ++j)
#pragma unroll
            for (int r = 0; r < 4; ++r) acc_o[j][r] *= ar_[r];

        // ---- p = exp(s - mnew), accumulate l, pack to Ps[wave][q][k] ----
#pragma unroll
        for (int mt = 0; mt < 4; ++mt) {
            float p0 = __expf(sv[mt * 4 + 0] - mnew);
            float p1 = __expf(sv[mt * 4 + 1] - mnew);
            float p2 = __expf(sv[mt * 4 + 2] - mnew);
            float p3 = __expf(sv[mt * 4 + 3] - mnew);
            l_run += (p0 + p1) + (p2 + p3);
            ushort4v pw;
            pw.x = f2bf_t(p0); pw.y = f2bf_t(p1); pw.z = f2bf_t(p2); pw.w = f2bf_t(p3);
            *(ushort4v*)(&Ps[wave][c * ATT_ST + mt * 16 + quad * 4]) = pw;
        }
        // same-wave LDS write->read: compiler inserts lgkmcnt wait; no barrier needed

        // ---- O += P·V ----
#pragma unroll
        for (int ks = 0; ks < 2; ++ks) {
            short8 pf = *(const short8*)(&Ps[wave][c * ATT_ST + ks * 32 + quad * 8]);
#pragma unroll
            for (int j = 0; j < 4; ++j) {
                short8 vf = *(const short8*)(&Vt[(j * 16 + c) * ATT_ST + ks * 32 + quad * 8]);
                acc_o[j] = __builtin_amdgcn_mfma_f32_16x16x32_bf16(pf, vf, acc_o[j], 0, 0, 0);
            }
        }
    }

    // ---- finalize: full l per q, normalize, write ----
    l_run += __shfl_xor(l_run, 16);
    l_run += __shfl_xor(l_run, 32);
    float li[4];
#pragma unroll
    for (int r = 0; r < 4; ++r) {
        float lv = __shfl(l_run, quad * 4 + r);
        li[r] = 1.0f / lv;
    }
#pragma unroll
    for (int r = 0; r < 4; ++r) {
        unsigned short* cp = Ctx + ((size_t)(b * Sn + qw + quad * 4 + r)) * Dn + h * 64 + c;
#pragma unroll
        for (int j = 0; j < 4; ++j) {
            cp[j * 16] = f2bf(acc_o[j][r] * li[r]);
        }
    }
}

// ---------------- launcher ----------------
extern "C" void kernel_launch(void* const* d_in, const int* in_sizes, int n_in,
                              void* d_out, int out_size, void* d_ws, size_t ws_size,
                              hipStream_t stream) {
    const float* x = (const float*)d_in[0];
    const int* lens = (const int*)d_in[1];
    const float* Wq = (const float*)d_in[2];
    const float* bq = (const float*)d_in[3];
    const float* Wkv = (const float*)d_in[4];
    const float* bkv = (const float*)d_in[5];
    const float* Wo = (const float*)d_in[6];
    const float* bo = (const float*)d_in[7];
    const float* ln_g = (const float*)d_in[8];
    const float* ln_b = (const float*)d_in[9];
    float* out = (float*)d_out;

    char* ws = (char*)d_ws;
    unsigned short* xn_bf = (unsigned short*)ws;                                // 16 MB
    unsigned short* wq_bf = (unsigned short*)(ws + (size_t)16 * 1024 * 1024);   // 2 MB
    unsigned short* wkv_bf = (unsigned short*)(ws + (size_t)18 * 1024 * 1024);  // 4 MB
    unsigned short* wo_bf = (unsigned short*)(ws + (size_t)22 * 1024 * 1024);   // 2 MB
    unsigned short* q_bf = (unsigned short*)(ws + (size_t)24 * 1024 * 1024);    // 16 MB
    unsigned short* kv_bf = (unsigned short*)(ws + (size_t)40 * 1024 * 1024);   // 32 MB
    unsigned short* ctx_bf = (unsigned short*)(ws + (size_t)72 * 1024 * 1024);  // 16 MB

    f2bf_kernel<<<(Dn * Dn / 4 + 255) / 256, 256, 0, stream>>>(Wq, wq_bf, Dn * Dn / 4);
    f2bf_kernel<<<(2 * Dn * Dn / 4 + 255) / 256, 256, 0, stream>>>(Wkv, wkv_bf, 2 * Dn * Dn / 4);
    f2bf_kernel<<<(Dn * Dn / 4 + 255) / 256, 256, 0, stream>>>(Wo, wo_bf, Dn * Dn / 4);

    ln_kernel<<<Mn, 256, 0, stream>>>(x, ln_g, ln_b, xn_bf);

    {
        dim3 grid(Mn / 128, Dn / 128);
        gemm_bt<false, true><<<grid, 256, 0, stream>>>(xn_bf, wq_bf, bq, nullptr,
                                                       (void*)q_bf, Mn, Dn, Dn);
    }
    {
        dim3 grid(Mn / 128, 2 * Dn / 128);
        gemm_bt<false, true><<<grid, 256, 0, stream>>>(xn_bf, wkv_bf, bkv, nullptr,
                                                       (void*)kv_bf, Mn, 2 * Dn, Dn);
    }
    {
        dim3 grid(Sn / 64, Hn, Bn);
        attn_kernel<<<grid, 256, 0, stream>>>(q_bf, kv_bf, lens, ctx_bf);
    }
    {
        dim3 grid(Mn / 128, Dn / 128);
        gemm_bt<true, false><<<grid, 256, 0, stream>>>(ctx_bf, wo_bf, bo, x,
                                                       (void*)out, Mn, Dn, Dn);
    }
}

// Round 3
// 288.937 us; speedup vs baseline: 4.2244x; 1.1223x over previous
//
#include <hip/hip_runtime.h>
#include <hip/hip_bf16.h>

// Problem: B=4, S=2048, D=1024, H=16, DH=64. M = B*S = 8192.
// Pipeline: LN -> Qproj(bf16 mfma) -> KVproj(bf16 mfma) -> flash attn (bf16 MFMA)
//           -> out proj + bias + skip (fp32 out)

#define Bn 4
#define Sn 2048
#define Dn 1024
#define Hn 16
#define DHn 64
#define Mn (Bn*Sn)

typedef short short8 __attribute__((ext_vector_type(8)));
typedef short short4v __attribute__((ext_vector_type(4)));
typedef unsigned short ushort8 __attribute__((ext_vector_type(8)));
typedef unsigned short ushort4v __attribute__((ext_vector_type(4)));
typedef float f32x4 __attribute__((ext_vector_type(4)));

__device__ inline float bf2f(unsigned short u) {
    union { unsigned int i; float f; } c;
    c.i = ((unsigned int)u) << 16;
    return c.f;
}

__device__ inline unsigned short f2bf(float f) {
    union { float f; unsigned int i; } c;
    c.f = f;
    unsigned int i = c.i;
    unsigned int lsb = (i >> 16) & 1;
    i += 0x7fffu + lsb;   // round-to-nearest-even
    return (unsigned short)(i >> 16);
}

// truncating fp32->bf16 (fine for p in [0,1])
__device__ inline unsigned short f2bf_t(float f) {
    union { float f; unsigned int i; } c;
    c.f = f;
    return (unsigned short)(c.i >> 16);
}

__device__ __forceinline__ float fast_exp2(float x) {
#if __has_builtin(__builtin_amdgcn_exp2f)
    return __builtin_amdgcn_exp2f(x);
#else
    return exp2f(x);
#endif
}

#if __has_builtin(__builtin_amdgcn_global_load_lds)
#define HAVE_GLDS 1
__device__ __forceinline__ void glds16(const void* g, void* l) {
    __builtin_amdgcn_global_load_lds(
        (const __attribute__((address_space(1))) unsigned int*)g,
        (__attribute__((address_space(3))) unsigned int*)l, 16, 0, 0);
}
#else
#define HAVE_GLDS 0
#endif

// ---------------- fp32 -> bf16 for all three weights, one launch ----------------
__global__ __launch_bounds__(256) void f2bf3_kernel(const float* __restrict__ Wq,
                                                    const float* __restrict__ Wkv,
                                                    const float* __restrict__ Wo,
                                                    unsigned short* __restrict__ oq,
                                                    unsigned short* __restrict__ okv,
                                                    unsigned short* __restrict__ oo) {
    int i = blockIdx.x * 256 + threadIdx.x;   // float4 index over 4M floats total
    const float* src;
    unsigned short* dst;
    int off;
    if (i < 262144) { src = Wq; dst = oq; off = i; }
    else if (i < 786432) { src = Wkv; dst = okv; off = i - 262144; }
    else { src = Wo; dst = oo; off = i - 786432; }
    float4 v = *(const float4*)(src + (size_t)off * 4);
    ushort4v r;
    r.x = f2bf(v.x); r.y = f2bf(v.y); r.z = f2bf(v.z); r.w = f2bf(v.w);
    *(ushort4v*)(dst + (size_t)off * 4) = r;
}

// ---------------- LayerNorm: fp32 in -> bf16 out ----------------
__global__ __launch_bounds__(256) void ln_kernel(const float* __restrict__ x,
                                                 const float* __restrict__ g,
                                                 const float* __restrict__ bta,
                                                 unsigned short* __restrict__ xn) {
    int row = blockIdx.x;
    int t = threadIdx.x;
    const float* xr = x + (size_t)row * Dn;
    float4 v = *(const float4*)(xr + t * 4);
    float s = v.x + v.y + v.z + v.w;
    float sq = v.x * v.x + v.y * v.y + v.z * v.z + v.w * v.w;
    for (int off = 32; off; off >>= 1) {
        s += __shfl_down(s, off);
        sq += __shfl_down(sq, off);
    }
    __shared__ float ss[4], ssq[4];
    int wave = t >> 6, lane = t & 63;
    if (lane == 0) { ss[wave] = s; ssq[wave] = sq; }
    __syncthreads();
    float tot = ss[0] + ss[1] + ss[2] + ss[3];
    float totq = ssq[0] + ssq[1] + ssq[2] + ssq[3];
    float mean = tot * (1.0f / Dn);
    float var = totq * (1.0f / Dn) - mean * mean;
    float rstd = rsqrtf(var + 1e-5f);
    float4 gv = *(const float4*)(g + t * 4);
    float4 bv = *(const float4*)(bta + t * 4);
    ushort4v r;
    r.x = f2bf((v.x - mean) * rstd * gv.x + bv.x);
    r.y = f2bf((v.y - mean) * rstd * gv.y + bv.y);
    r.z = f2bf((v.z - mean) * rstd * gv.z + bv.z);
    r.w = f2bf((v.w - mean) * rstd * gv.w + bv.w);
    *(ushort4v*)(xn + (size_t)row * Dn + t * 4) = r;
}

// ---------------- bf16 BT-GEMM: C = A(MxK) * Bw(NxK)^T + bias ----------------
// 128x128 tile, 4 waves, 4x4 16x16x32 MFMA per wave; global_load_lds width-16
// staging (m97 pattern): LDS dest = wave-uniform base + lane*16B.
template <bool ADD_SKIP, bool OUT_BF16>
__global__ __launch_bounds__(256, 2) void gemm_bt(const unsigned short* __restrict__ A,
                                                  const unsigned short* __restrict__ Bw,
                                                  const float* __restrict__ bias,
                                                  const float* __restrict__ skip,
                                                  void* __restrict__ Cout,
                                                  int M, int N, int K) {
    __shared__ unsigned short As[128 * 32];
    __shared__ unsigned short Bs[128 * 32];
    const int tid = threadIdx.x;
    const int wave = tid >> 6, lane = tid & 63;
    const int warp_m = wave & 1, warp_n = wave >> 1;
    const int bm = blockIdx.x, bn = blockIdx.y;
    const int l4 = lane & 3, lr = lane >> 2;
    const int quad = lane >> 4, r16 = lane & 15;

    f32x4 acc[4][4];
#pragma unroll
    for (int i = 0; i < 4; i++)
#pragma unroll
        for (int j = 0; j < 4; j++) acc[i][j] = (f32x4){0.f, 0.f, 0.f, 0.f};

    for (int k0 = 0; k0 < K; k0 += 32) {
        __syncthreads();   // prev iteration's fragment readers done
#if HAVE_GLDS
#pragma unroll
        for (int i = 0; i < 2; ++i) {
            int inst = wave + 4 * i;
            glds16(A + (size_t)(bm * 128 + inst * 16 + lr) * K + k0 + l4 * 8, &As[inst * 512]);
            glds16(Bw + (size_t)(bn * 128 + inst * 16 + lr) * K + k0 + l4 * 8, &Bs[inst * 512]);
        }
#else
#pragma unroll
        for (int i = 0; i < 2; ++i) {
            int inst = wave + 4 * i;
            int row = inst * 16 + lr;
            ushort8 a = *(const ushort8*)(A + (size_t)(bm * 128 + row) * K + k0 + l4 * 8);
            ushort8 b2 = *(const ushort8*)(Bw + (size_t)(bn * 128 + row) * K + k0 + l4 * 8);
            *(ushort8*)(As + inst * 512 + lane * 8) = a;
            *(ushort8*)(Bs + inst * 512 + lane * 8) = b2;
        }
#endif
        __syncthreads();   // vmcnt drain: LDS populated

        short8 afr[4], bfr[4];
#pragma unroll
        for (int i = 0; i < 4; ++i) {
            int row = warp_m * 64 + i * 16 + r16;
            afr[i] = *(const short8*)(As + row * 32 + quad * 8);
        }
#pragma unroll
        for (int j = 0; j < 4; ++j) {
            int row = warp_n * 64 + j * 16 + r16;
            bfr[j] = *(const short8*)(Bs + row * 32 + quad * 8);
        }
#pragma unroll
        for (int i = 0; i < 4; ++i)
#pragma unroll
            for (int j = 0; j < 4; ++j)
                acc[i][j] = __builtin_amdgcn_mfma_f32_16x16x32_bf16(afr[i], bfr[j], acc[i][j], 0, 0, 0);
    }

#pragma unroll
    for (int j = 0; j < 4; ++j) {
        int gcol = bn * 128 + warp_n * 64 + j * 16 + r16;
        float bv = bias[gcol];
#pragma unroll
        for (int i = 0; i < 4; ++i) {
#pragma unroll
            for (int r = 0; r < 4; ++r) {
                int grow = bm * 128 + warp_m * 64 + i * 16 + quad * 4 + r;
                float v = acc[i][j][r] + bv;
                size_t idx = (size_t)grow * N + gcol;
                if (ADD_SKIP) v += skip[idx];
                if (OUT_BF16)
                    ((unsigned short*)Cout)[idx] = f2bf(v);
                else
                    ((float*)Cout)[idx] = v;
            }
        }
    }
}

// ---------------- MFMA flash attention ----------------
// grid (S/64, H, B), 4 waves; wave w owns q rows [qt*64+w*16, +16).
// Per k-tile: S^T = K·Q^T (C layout: col q=lane&15, row k=mt*16+quad*4+reg),
// log2-domain online softmax, P relayout via per-wave LDS, O += P·V with
// V staged transposed. Vt stride 68 (writes/reads 4 lanes/bank-pair = free);
// Ks/Ps stride 72 (16B-aligned rows for b128).
#define STK 72
#define STV 68
#define STP 72

__global__ __launch_bounds__(256, 4) void attn_kernel(const unsigned short* __restrict__ Q,
                                                      const unsigned short* __restrict__ KV,
                                                      const int* __restrict__ lens,
                                                      unsigned short* __restrict__ Ctx) {
    const int qt = blockIdx.x, h = blockIdx.y, b = blockIdx.z;
    const int tid = threadIdx.x;
    const int wave = tid >> 6, lane = tid & 63;
    const int quad = lane >> 4, c = lane & 15;
    const int len = lens[b];
    const int qw = qt * 64 + wave * 16;
    const int myq = qw + c;

    __shared__ unsigned short Ks[64 * STK];
    __shared__ unsigned short Vt[64 * STV];
    __shared__ unsigned short Ps[4][16 * STP];

    short8 qfrag[2];
    {
        const unsigned short* qp2 = Q + ((size_t)(b * Sn + qw + c)) * Dn + h * 64 + quad * 8;
        qfrag[0] = *(const short8*)(qp2);
        qfrag[1] = *(const short8*)(qp2 + 32);
    }

    f32x4 acc_o[4];
#pragma unroll
    for (int j = 0; j < 4; j++) acc_o[j] = (f32x4){0.f, 0.f, 0.f, 0.f};
    float m_run = -1e30f, l_run = 0.f;

    // staging thread mappings
    const int krow = tid >> 2, dp = tid & 3;   // K: row krow, 16-col chunk dp
    const int kg = tid >> 4, dg = tid & 15;    // V: k rows kg*4..+3, dh cols dg*4..+3
    const unsigned short* kvb = KV + ((size_t)(b * Sn)) * (2 * Dn) + h * 64;

    // prologue: load tile 0 into registers
    ushort8 kr0, kr1;
    ushort4v vr0, vr1, vr2, vr3;
    {
        const unsigned short* kp2 = kvb + (size_t)krow * (2 * Dn) + dp * 16;
        kr0 = *(const ushort8*)(kp2);
        kr1 = *(const ushort8*)(kp2 + 8);
        const unsigned short* vp2 = kvb + Dn + (size_t)(kg * 4) * (2 * Dn) + dg * 4;
        vr0 = *(const ushort4v*)(vp2);
        vr1 = *(const ushort4v*)(vp2 + 2 * Dn);
        vr2 = *(const ushort4v*)(vp2 + 4 * Dn);
        vr3 = *(const ushort4v*)(vp2 + 6 * Dn);
    }

    const float C2 = 0.18033688011112042f;   // (1/sqrt(64)) * log2(e)
    const int ktend = min(qt, (len - 1) >> 6);
    for (int kt = 0; kt <= ktend; ++kt) {
        __syncthreads();   // prior iteration's LDS readers done
        // ---- write prefetched tile to LDS ----
        *(ushort8*)(&Ks[krow * STK + dp * 16]) = kr0;
        *(ushort8*)(&Ks[krow * STK + dp * 16 + 8]) = kr1;
#pragma unroll
        for (int w = 0; w < 4; ++w) {
            ushort4v t;
            t.x = vr0[w]; t.y = vr1[w]; t.z = vr2[w]; t.w = vr3[w];
            *(ushort4v*)(&Vt[(dg * 4 + w) * STV + kg * 4]) = t;
        }
        __syncthreads();

        // ---- issue next tile's global loads (overlap with compute below) ----
        if (kt < ktend) {
            const unsigned short* kp2 = kvb + (size_t)((kt + 1) * 64 + krow) * (2 * Dn) + dp * 16;
            kr0 = *(const ushort8*)(kp2);
            kr1 = *(const ushort8*)(kp2 + 8);
            const unsigned short* vp2 = kvb + Dn + (size_t)((kt + 1) * 64 + kg * 4) * (2 * Dn) + dg * 4;
            vr0 = *(const ushort4v*)(vp2);
            vr1 = *(const ushort4v*)(vp2 + 2 * Dn);
            vr2 = *(const ushort4v*)(vp2 + 4 * Dn);
            vr3 = *(const ushort4v*)(vp2 + 6 * Dn);
        }

        // ---- S^T = K·Q^T ----
        f32x4 sacc[4];
#pragma unroll
        for (int mt = 0; mt < 4; ++mt) sacc[mt] = (f32x4){0.f, 0.f, 0.f, 0.f};
#pragma unroll
        for (int mt = 0; mt < 4; ++mt) {
            short8 kf0 = *(const short8*)(&Ks[(mt * 16 + c) * STK + quad * 8]);
            short8 kf1 = *(const short8*)(&Ks[(mt * 16 + c) * STK + 32 + quad * 8]);
            sacc[mt] = __builtin_amdgcn_mfma_f32_16x16x32_bf16(kf0, qfrag[0], sacc[mt], 0, 0, 0);
            sacc[mt] = __builtin_amdgcn_mfma_f32_16x16x32_bf16(kf1, qfrag[1], sacc[mt], 0, 0, 0);
        }

        // ---- mask + per-q max (raw domain) ----
        const int kb = kt * 64;
        const bool full = (kb + 63 <= qw) && (kb + 64 <= len);   // tile valid for all lanes
        float sv[16];
        float mx = -1e30f;
        if (full) {
#pragma unroll
            for (int e = 0; e < 16; ++e) {
                float v = sacc[e >> 2][e & 3];
                sv[e] = v;
                mx = fmaxf(mx, v);
            }
        } else {
#pragma unroll
            for (int mt = 0; mt < 4; ++mt) {
#pragma unroll
                for (int r = 0; r < 4; ++r) {
                    int kpos = kb + mt * 16 + quad * 4 + r;
                    bool valid = (kpos <= myq) && (kpos < len);
                    float v = valid ? sacc[mt][r] : -1e30f;
                    sv[mt * 4 + r] = v;
                    mx = fmaxf(mx, v);
                }
            }
        }
        mx = fmaxf(mx, __shfl_xor(mx, 16));
        mx = fmaxf(mx, __shfl_xor(mx, 32));
        float mnew = fmaxf(m_run, mx * C2);   // log2 domain
        float alpha = fast_exp2(m_run - mnew);
        m_run = mnew;
        l_run *= alpha;

        // rescale O (alpha indexed by q=c; O rows are q = quad*4+r)
        float ar_[4];
#pragma unroll
        for (int r = 0; r < 4; ++r) ar_[r] = __shfl(alpha, quad * 4 + r);
#pragma unroll
        for (int j = 0; j < 4; ++j)
#pragma unroll
            for (int r = 0; r < 4; ++r) acc_o[j][r] *= ar_[r];

        // ---- p = exp2(s*C2 - mnew), accumulate l, pack to Ps ----
#pragma unroll
        for (int mt = 0; mt < 4; ++mt) {
            float p0 = fast_exp2(__builtin_fmaf(sv[mt * 4 + 0], C2, -mnew));
            float p1 = fast_exp2(__builtin_fmaf(sv[mt * 4 + 1], C2, -mnew));
            float p2 = fast_exp2(__builtin_fmaf(sv[mt * 4 + 2], C2, -mnew));
            float p3 = fast_exp2(__builtin_fmaf(sv[mt * 4 + 3], C2, -mnew));
            l_run += (p0 + p1) + (p2 + p3);
            ushort4v pw;
            pw.x = f2bf_t(p0); pw.y = f2bf_t(p1); pw.z = f2bf_t(p2); pw.w = f2bf_t(p3);
            *(ushort4v*)(&Ps[wave][c * STP + mt * 16 + quad * 4]) = pw;
        }
        // same-wave LDS write->read: compiler inserts lgkmcnt wait; no barrier needed

        // ---- O += P·V ----
#pragma unroll
        for (int ks = 0; ks < 2; ++ks) {
            short8 pf = *(const short8*)(&Ps[wave][c * STP + ks * 32 + quad * 8]);
#pragma unroll
            for (int j = 0; j < 4; ++j) {
                const unsigned short* vb2 = &Vt[(j * 16 + c) * STV + ks * 32 + quad * 8];
                short4v a0 = *(const short4v*)(vb2);
                short4v a1 = *(const short4v*)(vb2 + 4);
                short8 vf = __builtin_shufflevector(a0, a1, 0, 1, 2, 3, 4, 5, 6, 7);
                acc_o[j] = __builtin_amdgcn_mfma_f32_16x16x32_bf16(pf, vf, acc_o[j], 0, 0, 0);
            }
        }
    }

    // ---- finalize ----
    l_run += __shfl_xor(l_run, 16);
    l_run += __shfl_xor(l_run, 32);
    float li[4];
#pragma unroll
    for (int r = 0; r < 4; ++r) {
        float lv = __shfl(l_run, quad * 4 + r);
        li[r] = 1.0f / lv;
    }
#pragma unroll
    for (int r = 0; r < 4; ++r) {
        unsigned short* cp = Ctx + ((size_t)(b * Sn + qw + quad * 4 + r)) * Dn + h * 64 + c;
#pragma unroll
        for (int j = 0; j < 4; ++j) {
            cp[j * 16] = f2bf(acc_o[j][r] * li[r]);
        }
    }
}

// ---------------- launcher ----------------
extern "C" void kernel_launch(void* const* d_in, const int* in_sizes, int n_in,
                              void* d_out, int out_size, void* d_ws, size_t ws_size,
                              hipStream_t stream) {
    const float* x = (const float*)d_in[0];
    const int* lens = (const int*)d_in[1];
    const float* Wq = (const float*)d_in[2];
    const float* bq = (const float*)d_in[3];
    const float* Wkv = (const float*)d_in[4];
    const float* bkv = (const float*)d_in[5];
    const float* Wo = (const float*)d_in[6];
    const float* bo = (const float*)d_in[7];
    const float* ln_g = (const float*)d_in[8];
    const float* ln_b = (const float*)d_in[9];
    float* out = (float*)d_out;

    char* ws = (char*)d_ws;
    unsigned short* xn_bf = (unsigned short*)ws;                                // 16 MB
    unsigned short* wq_bf = (unsigned short*)(ws + (size_t)16 * 1024 * 1024);   // 2 MB
    unsigned short* wkv_bf = (unsigned short*)(ws + (size_t)18 * 1024 * 1024);  // 4 MB
    unsigned short* wo_bf = (unsigned short*)(ws + (size_t)22 * 1024 * 1024);   // 2 MB
    unsigned short* q_bf = (unsigned short*)(ws + (size_t)24 * 1024 * 1024);    // 16 MB
    unsigned short* kv_bf = (unsigned short*)(ws + (size_t)40 * 1024 * 1024);   // 32 MB
    unsigned short* ctx_bf = (unsigned short*)(ws + (size_t)72 * 1024 * 1024);  // 16 MB

    f2bf3_kernel<<<4096, 256, 0, stream>>>(Wq, Wkv, Wo, wq_bf, wkv_bf, wo_bf);

    ln_kernel<<<Mn, 256, 0, stream>>>(x, ln_g, ln_b, xn_bf);

    {
        dim3 grid(Mn / 128, Dn / 128);
        gemm_bt<false, true><<<grid, 256, 0, stream>>>(xn_bf, wq_bf, bq, nullptr,
                                                       (void*)q_bf, Mn, Dn, Dn);
    }
    {
        dim3 grid(Mn / 128, 2 * Dn / 128);
        gemm_bt<false, true><<<grid, 256, 0, stream>>>(xn_bf, wkv_bf, bkv, nullptr,
                                                       (void*)kv_bf, Mn, 2 * Dn, Dn);
    }
    {
        dim3 grid(Sn / 64, Hn, Bn);
        attn_kernel<<<grid, 256, 0, stream>>>(q_bf, kv_bf, lens, ctx_bf);
    }
    {
        dim3 grid(Mn / 128, Dn / 128);
        gemm_bt<true, false><<<grid, 256, 0, stream>>>(ctx_bf, wo_bf, bo, x,
                                                       (void*)out, Mn, Dn, Dn);
    }
}

// Round 4
// 270.234 us; speedup vs baseline: 4.5168x; 1.0692x over previous
//
#include <hip/hip_runtime.h>
#include <hip/hip_bf16.h>

// Problem: B=4, S=2048, D=1024, H=16, DH=64. M = B*S = 8192.
// Pipeline: LN -> fused QKV proj (bf16 mfma, N=3072) -> flash attn (bf16 MFMA,
//           paired q-tiles for load balance) -> out proj + bias + skip (fp32 out)

#define Bn 4
#define Sn 2048
#define Dn 1024
#define Hn 16
#define DHn 64
#define Mn (Bn*Sn)

typedef short short8 __attribute__((ext_vector_type(8)));
typedef short short4v __attribute__((ext_vector_type(4)));
typedef unsigned short ushort8 __attribute__((ext_vector_type(8)));
typedef unsigned short ushort4v __attribute__((ext_vector_type(4)));
typedef float f32x4 __attribute__((ext_vector_type(4)));

__device__ inline float bf2f(unsigned short u) {
    union { unsigned int i; float f; } c;
    c.i = ((unsigned int)u) << 16;
    return c.f;
}

__device__ inline unsigned short f2bf(float f) {
    union { float f; unsigned int i; } c;
    c.f = f;
    unsigned int i = c.i;
    unsigned int lsb = (i >> 16) & 1;
    i += 0x7fffu + lsb;   // round-to-nearest-even
    return (unsigned short)(i >> 16);
}

// truncating fp32->bf16 (fine for p in [0,1])
__device__ inline unsigned short f2bf_t(float f) {
    union { float f; unsigned int i; } c;
    c.f = f;
    return (unsigned short)(c.i >> 16);
}

__device__ __forceinline__ float fast_exp2(float x) {
#if __has_builtin(__builtin_amdgcn_exp2f)
    return __builtin_amdgcn_exp2f(x);
#else
    return exp2f(x);
#endif
}

#if __has_builtin(__builtin_amdgcn_global_load_lds)
#define HAVE_GLDS 1
__device__ __forceinline__ void glds16(const void* g, void* l) {
    __builtin_amdgcn_global_load_lds(
        (const __attribute__((address_space(1))) unsigned int*)g,
        (__attribute__((address_space(3))) unsigned int*)l, 16, 0, 0);
}
#else
#define HAVE_GLDS 0
#endif

// ---------------- fp32 -> bf16 for all three weights, one launch ----------------
__global__ __launch_bounds__(256) void f2bf3_kernel(const float* __restrict__ Wq,
                                                    const float* __restrict__ Wkv,
                                                    const float* __restrict__ Wo,
                                                    unsigned short* __restrict__ oq,
                                                    unsigned short* __restrict__ okv,
                                                    unsigned short* __restrict__ oo) {
    int i = blockIdx.x * 256 + threadIdx.x;   // float4 index over 4M floats total
    const float* src;
    unsigned short* dst;
    int off;
    if (i < 262144) { src = Wq; dst = oq; off = i; }
    else if (i < 786432) { src = Wkv; dst = okv; off = i - 262144; }
    else { src = Wo; dst = oo; off = i - 786432; }
    float4 v = *(const float4*)(src + (size_t)off * 4);
    ushort4v r;
    r.x = f2bf(v.x); r.y = f2bf(v.y); r.z = f2bf(v.z); r.w = f2bf(v.w);
    *(ushort4v*)(dst + (size_t)off * 4) = r;
}

// ---------------- LayerNorm: fp32 in -> bf16 out ----------------
__global__ __launch_bounds__(256) void ln_kernel(const float* __restrict__ x,
                                                 const float* __restrict__ g,
                                                 const float* __restrict__ bta,
                                                 unsigned short* __restrict__ xn) {
    int row = blockIdx.x;
    int t = threadIdx.x;
    const float* xr = x + (size_t)row * Dn;
    float4 v = *(const float4*)(xr + t * 4);
    float s = v.x + v.y + v.z + v.w;
    float sq = v.x * v.x + v.y * v.y + v.z * v.z + v.w * v.w;
    for (int off = 32; off; off >>= 1) {
        s += __shfl_down(s, off);
        sq += __shfl_down(sq, off);
    }
    __shared__ float ss[4], ssq[4];
    int wave = t >> 6, lane = t & 63;
    if (lane == 0) { ss[wave] = s; ssq[wave] = sq; }
    __syncthreads();
    float tot = ss[0] + ss[1] + ss[2] + ss[3];
    float totq = ssq[0] + ssq[1] + ssq[2] + ssq[3];
    float mean = tot * (1.0f / Dn);
    float var = totq * (1.0f / Dn) - mean * mean;
    float rstd = rsqrtf(var + 1e-5f);
    float4 gv = *(const float4*)(g + t * 4);
    float4 bv = *(const float4*)(bta + t * 4);
    ushort4v r;
    r.x = f2bf((v.x - mean) * rstd * gv.x + bv.x);
    r.y = f2bf((v.y - mean) * rstd * gv.y + bv.y);
    r.z = f2bf((v.z - mean) * rstd * gv.z + bv.z);
    r.w = f2bf((v.w - mean) * rstd * gv.w + bv.w);
    *(ushort4v*)(xn + (size_t)row * Dn + t * 4) = r;
}

// ---------------- bf16 BT-GEMM: C = A(MxK) * Bw(NxK)^T + bias ----------------
// 128x128 tile, 4 waves, 4x4 16x16x32 MFMA per wave; global_load_lds width-16.
// Bias selected per block: cols < bsplit use bias, else bias2[col - bsplit].
template <bool ADD_SKIP, bool OUT_BF16>
__global__ __launch_bounds__(256, 2) void gemm_bt(const unsigned short* __restrict__ A,
                                                  const unsigned short* __restrict__ Bw,
                                                  const float* __restrict__ bias,
                                                  const float* __restrict__ bias2,
                                                  int bsplit,
                                                  const float* __restrict__ skip,
                                                  void* __restrict__ Cout,
                                                  int M, int N, int K) {
    __shared__ unsigned short As[128 * 32];
    __shared__ unsigned short Bs[128 * 32];
    const int tid = threadIdx.x;
    const int wave = tid >> 6, lane = tid & 63;
    const int warp_m = wave & 1, warp_n = wave >> 1;
    const int bm = blockIdx.x, bn = blockIdx.y;
    const int l4 = lane & 3, lr = lane >> 2;
    const int quad = lane >> 4, r16 = lane & 15;

    f32x4 acc[4][4];
#pragma unroll
    for (int i = 0; i < 4; i++)
#pragma unroll
        for (int j = 0; j < 4; j++) acc[i][j] = (f32x4){0.f, 0.f, 0.f, 0.f};

    for (int k0 = 0; k0 < K; k0 += 32) {
        __syncthreads();   // prev iteration's fragment readers done
#if HAVE_GLDS
#pragma unroll
        for (int i = 0; i < 2; ++i) {
            int inst = wave + 4 * i;
            glds16(A + (size_t)(bm * 128 + inst * 16 + lr) * K + k0 + l4 * 8, &As[inst * 512]);
            glds16(Bw + (size_t)(bn * 128 + inst * 16 + lr) * K + k0 + l4 * 8, &Bs[inst * 512]);
        }
#else
#pragma unroll
        for (int i = 0; i < 2; ++i) {
            int inst = wave + 4 * i;
            int row = inst * 16 + lr;
            ushort8 a = *(const ushort8*)(A + (size_t)(bm * 128 + row) * K + k0 + l4 * 8);
            ushort8 b2 = *(const ushort8*)(Bw + (size_t)(bn * 128 + row) * K + k0 + l4 * 8);
            *(ushort8*)(As + inst * 512 + lane * 8) = a;
            *(ushort8*)(Bs + inst * 512 + lane * 8) = b2;
        }
#endif
        __syncthreads();   // vmcnt drain: LDS populated

        short8 afr[4], bfr[4];
#pragma unroll
        for (int i = 0; i < 4; ++i) {
            int row = warp_m * 64 + i * 16 + r16;
            afr[i] = *(const short8*)(As + row * 32 + quad * 8);
        }
#pragma unroll
        for (int j = 0; j < 4; ++j) {
            int row = warp_n * 64 + j * 16 + r16;
            bfr[j] = *(const short8*)(Bs + row * 32 + quad * 8);
        }
#pragma unroll
        for (int i = 0; i < 4; ++i)
#pragma unroll
            for (int j = 0; j < 4; ++j)
                acc[i][j] = __builtin_amdgcn_mfma_f32_16x16x32_bf16(afr[i], bfr[j], acc[i][j], 0, 0, 0);
    }

    const float* bp = (bn * 128 >= bsplit) ? (bias2 - bsplit) : bias;
#pragma unroll
    for (int j = 0; j < 4; ++j) {
        int gcol = bn * 128 + warp_n * 64 + j * 16 + r16;
        float bv = bp[gcol];
#pragma unroll
        for (int i = 0; i < 4; ++i) {
#pragma unroll
            for (int r = 0; r < 4; ++r) {
                int grow = bm * 128 + warp_m * 64 + i * 16 + quad * 4 + r;
                float v = acc[i][j][r] + bv;
                size_t idx = (size_t)grow * N + gcol;
                if (ADD_SKIP) v += skip[idx];
                if (OUT_BF16)
                    ((unsigned short*)Cout)[idx] = f2bf(v);
                else
                    ((float*)Cout)[idx] = v;
            }
        }
    }
}

// ---------------- MFMA flash attention, paired q-tiles ----------------
// grid (S/128, H, B): block handles q-tiles qtA=bx and qtB=31-bx (constant
// total work), sharing K/V staging. 4 waves; wave w owns rows w*16..+16 of
// BOTH tiles. Per k-tile: S^T = K·Q^T, log2-domain online softmax, P via
// per-wave LDS, O += P·V with V staged transposed.
#define STK 72
#define STV 68
#define STP 72
#define QKVS (3 * Dn)   // fused QKV row stride

__global__ __launch_bounds__(256, 4) void attn_kernel(const unsigned short* __restrict__ QKV,
                                                      const int* __restrict__ lens,
                                                      unsigned short* __restrict__ Ctx) {
    const int h = blockIdx.y, b = blockIdx.z;
    const int qtA = blockIdx.x;                 // 0..15
    const int qtB = (Sn / 64 - 1) - qtA;        // 31..16
    const int tid = threadIdx.x;
    const int wave = tid >> 6, lane = tid & 63;
    const int quad = lane >> 4, c = lane & 15;
    const int len = lens[b];
    const int lt = (len - 1) >> 6;
    const int ktendA = min(qtA, lt);
    const int ktendB = min(qtB, lt);            // >= ktendA always
    const int qwA = qtA * 64 + wave * 16;
    const int qwB = qtB * 64 + wave * 16;
    const int myqA = qwA + c, myqB = qwB + c;

    __shared__ unsigned short Ks[64 * STK];
    __shared__ unsigned short Vt[64 * STV];
    __shared__ unsigned short Ps[4][16 * STP];

    // Q fragments for both chunks (B-operand layout)
    short8 qfA[2], qfB[2];
    {
        const unsigned short* qa = QKV + (size_t)(b * Sn + qwA + c) * QKVS + h * 64 + quad * 8;
        qfA[0] = *(const short8*)(qa);
        qfA[1] = *(const short8*)(qa + 32);
        const unsigned short* qb = QKV + (size_t)(b * Sn + qwB + c) * QKVS + h * 64 + quad * 8;
        qfB[0] = *(const short8*)(qb);
        qfB[1] = *(const short8*)(qb + 32);
    }

    f32x4 accA[4], accB[4];
#pragma unroll
    for (int j = 0; j < 4; j++) {
        accA[j] = (f32x4){0.f, 0.f, 0.f, 0.f};
        accB[j] = (f32x4){0.f, 0.f, 0.f, 0.f};
    }
    float mA = -1e30f, lA = 0.f, mB = -1e30f, lB = 0.f;

    // staging thread mappings
    const int krow = tid >> 2, dp = tid & 3;   // K: row krow, 16-col chunk dp
    const int kg = tid >> 4, dg = tid & 15;    // V: k rows kg*4..+3, dh cols dg*4..+3
    const unsigned short* kbase = QKV + (size_t)(b * Sn) * QKVS + Dn + h * 64;        // K cols
    const unsigned short* vbase = QKV + (size_t)(b * Sn) * QKVS + 2 * Dn + h * 64;    // V cols

    // prologue: prefetch tile 0
    ushort8 kr0, kr1;
    ushort4v vr0, vr1, vr2, vr3;
    {
        const unsigned short* kp2 = kbase + (size_t)krow * QKVS + dp * 16;
        kr0 = *(const ushort8*)(kp2);
        kr1 = *(const ushort8*)(kp2 + 8);
        const unsigned short* vp2 = vbase + (size_t)(kg * 4) * QKVS + dg * 4;
        vr0 = *(const ushort4v*)(vp2);
        vr1 = *(const ushort4v*)(vp2 + QKVS);
        vr2 = *(const ushort4v*)(vp2 + 2 * QKVS);
        vr3 = *(const ushort4v*)(vp2 + 3 * QKVS);
    }

    const float C2 = 0.18033688011112042f;   // (1/sqrt(64)) * log2(e)

    // per-chunk compute: S^T -> softmax -> P -> O += P·V
    auto process = [&](int kt, const short8* qf, f32x4* acc_o, float& m_run, float& l_run,
                       int qw, int myq) {
        f32x4 sacc[4];
#pragma unroll
        for (int mt = 0; mt < 4; ++mt) sacc[mt] = (f32x4){0.f, 0.f, 0.f, 0.f};
#pragma unroll
        for (int mt = 0; mt < 4; ++mt) {
            short8 kf0 = *(const short8*)(&Ks[(mt * 16 + c) * STK + quad * 8]);
            short8 kf1 = *(const short8*)(&Ks[(mt * 16 + c) * STK + 32 + quad * 8]);
            sacc[mt] = __builtin_amdgcn_mfma_f32_16x16x32_bf16(kf0, qf[0], sacc[mt], 0, 0, 0);
            sacc[mt] = __builtin_amdgcn_mfma_f32_16x16x32_bf16(kf1, qf[1], sacc[mt], 0, 0, 0);
        }

        const int kb = kt * 64;
        const bool full = (kb + 63 <= qw) && (kb + 64 <= len);
        float sv[16];
        float mx = -1e30f;
        if (full) {
#pragma unroll
            for (int e = 0; e < 16; ++e) {
                float v = sacc[e >> 2][e & 3];
                sv[e] = v;
                mx = fmaxf(mx, v);
            }
        } else {
#pragma unroll
            for (int mt = 0; mt < 4; ++mt) {
#pragma unroll
                for (int r = 0; r < 4; ++r) {
                    int kpos = kb + mt * 16 + quad * 4 + r;
                    bool valid = (kpos <= myq) && (kpos < len);
                    float v = valid ? sacc[mt][r] : -1e30f;
                    sv[mt * 4 + r] = v;
                    mx = fmaxf(mx, v);
                }
            }
        }
        mx = fmaxf(mx, __shfl_xor(mx, 16));
        mx = fmaxf(mx, __shfl_xor(mx, 32));
        float mnew = fmaxf(m_run, mx * C2);   // log2 domain
        float alpha = fast_exp2(m_run - mnew);
        m_run = mnew;
        l_run *= alpha;

        float ar_[4];
#pragma unroll
        for (int r = 0; r < 4; ++r) ar_[r] = __shfl(alpha, quad * 4 + r);
#pragma unroll
        for (int j = 0; j < 4; ++j)
#pragma unroll
            for (int r = 0; r < 4; ++r) acc_o[j][r] *= ar_[r];

#pragma unroll
        for (int mt = 0; mt < 4; ++mt) {
            float p0 = fast_exp2(__builtin_fmaf(sv[mt * 4 + 0], C2, -mnew));
            float p1 = fast_exp2(__builtin_fmaf(sv[mt * 4 + 1], C2, -mnew));
            float p2 = fast_exp2(__builtin_fmaf(sv[mt * 4 + 2], C2, -mnew));
            float p3 = fast_exp2(__builtin_fmaf(sv[mt * 4 + 3], C2, -mnew));
            l_run += (p0 + p1) + (p2 + p3);
            ushort4v pw;
            pw.x = f2bf_t(p0); pw.y = f2bf_t(p1); pw.z = f2bf_t(p2); pw.w = f2bf_t(p3);
            *(ushort4v*)(&Ps[wave][c * STP + mt * 16 + quad * 4]) = pw;
        }
        // same-wave LDS ordering: DS ops in-order, no barrier needed

#pragma unroll
        for (int ks = 0; ks < 2; ++ks) {
            short8 pf = *(const short8*)(&Ps[wave][c * STP + ks * 32 + quad * 8]);
#pragma unroll
            for (int j = 0; j < 4; ++j) {
                const unsigned short* vb2 = &Vt[(j * 16 + c) * STV + ks * 32 + quad * 8];
                short4v a0 = *(const short4v*)(vb2);
                short4v a1 = *(const short4v*)(vb2 + 4);
                short8 vf = __builtin_shufflevector(a0, a1, 0, 1, 2, 3, 4, 5, 6, 7);
                acc_o[j] = __builtin_amdgcn_mfma_f32_16x16x32_bf16(pf, vf, acc_o[j], 0, 0, 0);
            }
        }
    };

    for (int kt = 0; kt <= ktendB; ++kt) {
        __syncthreads();   // prior iteration's LDS readers done
        // write prefetched tile to LDS
        *(ushort8*)(&Ks[krow * STK + dp * 16]) = kr0;
        *(ushort8*)(&Ks[krow * STK + dp * 16 + 8]) = kr1;
#pragma unroll
        for (int w = 0; w < 4; ++w) {
            ushort4v t;
            t.x = vr0[w]; t.y = vr1[w]; t.z = vr2[w]; t.w = vr3[w];
            *(ushort4v*)(&Vt[(dg * 4 + w) * STV + kg * 4]) = t;
        }
        __syncthreads();

        // issue next tile's global loads (overlap with compute below)
        if (kt < ktendB) {
            const unsigned short* kp2 = kbase + (size_t)((kt + 1) * 64 + krow) * QKVS + dp * 16;
            kr0 = *(const ushort8*)(kp2);
            kr1 = *(const ushort8*)(kp2 + 8);
            const unsigned short* vp2 = vbase + (size_t)((kt + 1) * 64 + kg * 4) * QKVS + dg * 4;
            vr0 = *(const ushort4v*)(vp2);
            vr1 = *(const ushort4v*)(vp2 + QKVS);
            vr2 = *(const ushort4v*)(vp2 + 2 * QKVS);
            vr3 = *(const ushort4v*)(vp2 + 3 * QKVS);
        }

        if (kt <= ktendA)
            process(kt, qfA, accA, mA, lA, qwA, myqA);
        process(kt, qfB, accB, mB, lB, qwB, myqB);
    }

    // ---- finalize both chunks ----
    auto finalize = [&](f32x4* acc_o, float l_run, int qw) {
        l_run += __shfl_xor(l_run, 16);
        l_run += __shfl_xor(l_run, 32);
        float li[4];
#pragma unroll
        for (int r = 0; r < 4; ++r) {
            float lv = __shfl(l_run, quad * 4 + r);
            li[r] = 1.0f / lv;
        }
#pragma unroll
        for (int r = 0; r < 4; ++r) {
            unsigned short* cp = Ctx + ((size_t)(b * Sn + qw + quad * 4 + r)) * Dn + h * 64 + c;
#pragma unroll
            for (int j = 0; j < 4; ++j) {
                cp[j * 16] = f2bf(acc_o[j][r] * li[r]);
            }
        }
    };
    finalize(accA, lA, qwA);
    finalize(accB, lB, qwB);
}

// ---------------- launcher ----------------
extern "C" void kernel_launch(void* const* d_in, const int* in_sizes, int n_in,
                              void* d_out, int out_size, void* d_ws, size_t ws_size,
                              hipStream_t stream) {
    const float* x = (const float*)d_in[0];
    const int* lens = (const int*)d_in[1];
    const float* Wq = (const float*)d_in[2];
    const float* bq = (const float*)d_in[3];
    const float* Wkv = (const float*)d_in[4];
    const float* bkv = (const float*)d_in[5];
    const float* Wo = (const float*)d_in[6];
    const float* bo = (const float*)d_in[7];
    const float* ln_g = (const float*)d_in[8];
    const float* ln_b = (const float*)d_in[9];
    float* out = (float*)d_out;

    char* ws = (char*)d_ws;
    unsigned short* xn_bf = (unsigned short*)ws;                                // 16 MB
    unsigned short* wq_bf = (unsigned short*)(ws + (size_t)16 * 1024 * 1024);   // 2 MB  (Wq | Wkv contiguous -> N=3072 weight)
    unsigned short* wkv_bf = (unsigned short*)(ws + (size_t)18 * 1024 * 1024);  // 4 MB
    unsigned short* wo_bf = (unsigned short*)(ws + (size_t)22 * 1024 * 1024);   // 2 MB
    unsigned short* qkv_bf = (unsigned short*)(ws + (size_t)24 * 1024 * 1024);  // 48 MB (M x 3072)
    unsigned short* ctx_bf = (unsigned short*)(ws + (size_t)72 * 1024 * 1024);  // 16 MB

    f2bf3_kernel<<<4096, 256, 0, stream>>>(Wq, Wkv, Wo, wq_bf, wkv_bf, wo_bf);

    ln_kernel<<<Mn, 256, 0, stream>>>(x, ln_g, ln_b, xn_bf);

    // fused QKV = xn @ [Wq;Wkv]^T + [bq;bkv]  (bf16 out, M x 3072)
    {
        dim3 grid(Mn / 128, 3 * Dn / 128);
        gemm_bt<false, true><<<grid, 256, 0, stream>>>(xn_bf, wq_bf, bq, bkv, Dn, nullptr,
                                                       (void*)qkv_bf, Mn, 3 * Dn, Dn);
    }
    // attention -> ctx bf16
    {
        dim3 grid(Sn / 128, Hn, Bn);
        attn_kernel<<<grid, 256, 0, stream>>>(qkv_bf, lens, ctx_bf);
    }
    // out = ctx @ Wo^T + bo + x   (fp32 out)
    {
        dim3 grid(Mn / 128, Dn / 128);
        gemm_bt<true, false><<<grid, 256, 0, stream>>>(ctx_bf, wo_bf, bo, bo, Dn, x,
                                                       (void*)out, Mn, Dn, Dn);
    }
}

// Round 5
// 268.933 us; speedup vs baseline: 4.5386x; 1.0048x over previous
//
#include <hip/hip_runtime.h>
#include <hip/hip_bf16.h>

// Problem: B=4, S=2048, D=1024, H=16, DH=64. M = B*S = 8192.
// Pipeline: prep(LN + weight cast) -> fused QKV proj (bf16 mfma, N=3072)
//           -> flash attn (bf16 MFMA, paired q-tiles) -> out proj (64-row
//           tiles for occupancy) + bias + skip (fp32 out)

#define Bn 4
#define Sn 2048
#define Dn 1024
#define Hn 16
#define DHn 64
#define Mn (Bn*Sn)

typedef short short8 __attribute__((ext_vector_type(8)));
typedef short short4v __attribute__((ext_vector_type(4)));
typedef unsigned short ushort8 __attribute__((ext_vector_type(8)));
typedef unsigned short ushort4v __attribute__((ext_vector_type(4)));
typedef float f32x4 __attribute__((ext_vector_type(4)));

__device__ inline float bf2f(unsigned short u) {
    union { unsigned int i; float f; } c;
    c.i = ((unsigned int)u) << 16;
    return c.f;
}

__device__ inline unsigned short f2bf(float f) {
    union { float f; unsigned int i; } c;
    c.f = f;
    unsigned int i = c.i;
    unsigned int lsb = (i >> 16) & 1;
    i += 0x7fffu + lsb;   // round-to-nearest-even
    return (unsigned short)(i >> 16);
}

// truncating fp32->bf16 (fine for p in [0,1])
__device__ inline unsigned short f2bf_t(float f) {
    union { float f; unsigned int i; } c;
    c.f = f;
    return (unsigned short)(c.i >> 16);
}

__device__ __forceinline__ float fast_exp2(float x) {
#if __has_builtin(__builtin_amdgcn_exp2f)
    return __builtin_amdgcn_exp2f(x);
#else
    return exp2f(x);
#endif
}

#if __has_builtin(__builtin_amdgcn_global_load_lds)
#define HAVE_GLDS 1
__device__ __forceinline__ void glds16(const void* g, void* l) {
    __builtin_amdgcn_global_load_lds(
        (const __attribute__((address_space(1))) unsigned int*)g,
        (__attribute__((address_space(3))) unsigned int*)l, 16, 0, 0);
}
#else
#define HAVE_GLDS 0
#endif

// ---------------- prep: LN (blocks 0..8191) + weight casts (blocks 8192..12287) ----------------
__global__ __launch_bounds__(256) void prep_kernel(const float* __restrict__ x,
                                                   const float* __restrict__ g,
                                                   const float* __restrict__ bta,
                                                   unsigned short* __restrict__ xn,
                                                   const float* __restrict__ Wq,
                                                   const float* __restrict__ Wkv,
                                                   const float* __restrict__ Wo,
                                                   unsigned short* __restrict__ oq,
                                                   unsigned short* __restrict__ okv,
                                                   unsigned short* __restrict__ oo) {
    const int t = threadIdx.x;
    if (blockIdx.x >= Mn) {
        // weight cast: 4096 blocks x 256 threads x float4 over 4M floats
        int i = (blockIdx.x - Mn) * 256 + t;
        const float* src;
        unsigned short* dst;
        int off;
        if (i < 262144) { src = Wq; dst = oq; off = i; }
        else if (i < 786432) { src = Wkv; dst = okv; off = i - 262144; }
        else { src = Wo; dst = oo; off = i - 786432; }
        float4 v = *(const float4*)(src + (size_t)off * 4);
        ushort4v r;
        r.x = f2bf(v.x); r.y = f2bf(v.y); r.z = f2bf(v.z); r.w = f2bf(v.w);
        *(ushort4v*)(dst + (size_t)off * 4) = r;
        return;
    }
    const int row = blockIdx.x;
    const float* xr = x + (size_t)row * Dn;
    float4 v = *(const float4*)(xr + t * 4);
    float s = v.x + v.y + v.z + v.w;
    float sq = v.x * v.x + v.y * v.y + v.z * v.z + v.w * v.w;
    for (int off = 32; off; off >>= 1) {
        s += __shfl_down(s, off);
        sq += __shfl_down(sq, off);
    }
    __shared__ float ss[4], ssq[4];
    int wave = t >> 6, lane = t & 63;
    if (lane == 0) { ss[wave] = s; ssq[wave] = sq; }
    __syncthreads();
    float tot = ss[0] + ss[1] + ss[2] + ss[3];
    float totq = ssq[0] + ssq[1] + ssq[2] + ssq[3];
    float mean = tot * (1.0f / Dn);
    float var = totq * (1.0f / Dn) - mean * mean;
    float rstd = rsqrtf(var + 1e-5f);
    float4 gv = *(const float4*)(g + t * 4);
    float4 bv = *(const float4*)(bta + t * 4);
    ushort4v r;
    r.x = f2bf((v.x - mean) * rstd * gv.x + bv.x);
    r.y = f2bf((v.y - mean) * rstd * gv.y + bv.y);
    r.z = f2bf((v.z - mean) * rstd * gv.z + bv.z);
    r.w = f2bf((v.w - mean) * rstd * gv.w + bv.w);
    *(ushort4v*)(xn + (size_t)row * Dn + t * 4) = r;
}

// ---------------- bf16 BT-GEMM: C = A(MxK) * Bw(NxK)^T + bias ----------------
// BMT x 128 tile (BMT = 128 or 64), 4 waves (2x2), 16x16x32 MFMA,
// global_load_lds width-16 staging. Bias per block: cols < bsplit use bias,
// else bias2[col - bsplit].
template <int BMT, bool ADD_SKIP, bool OUT_BF16>
__global__ __launch_bounds__(256, 2) void gemm_bt(const unsigned short* __restrict__ A,
                                                  const unsigned short* __restrict__ Bw,
                                                  const float* __restrict__ bias,
                                                  const float* __restrict__ bias2,
                                                  int bsplit,
                                                  const float* __restrict__ skip,
                                                  void* __restrict__ Cout,
                                                  int M, int N, int K) {
    constexpr int AI = BMT / 64;   // A staging glds16 per thread
    constexpr int MI = BMT / 32;   // m-tiles per wave
    __shared__ unsigned short As[BMT * 32];
    __shared__ unsigned short Bs[128 * 32];
    const int tid = threadIdx.x;
    const int wave = tid >> 6, lane = tid & 63;
    const int warp_m = wave & 1, warp_n = wave >> 1;
    const int bm = blockIdx.x, bn = blockIdx.y;
    const int l4 = lane & 3, lr = lane >> 2;
    const int quad = lane >> 4, r16 = lane & 15;

    f32x4 acc[MI][4];
#pragma unroll
    for (int i = 0; i < MI; i++)
#pragma unroll
        for (int j = 0; j < 4; j++) acc[i][j] = (f32x4){0.f, 0.f, 0.f, 0.f};

    for (int k0 = 0; k0 < K; k0 += 32) {
        __syncthreads();   // prev iteration's fragment readers done
#if HAVE_GLDS
#pragma unroll
        for (int i = 0; i < AI; ++i) {
            int inst = wave + 4 * i;
            glds16(A + (size_t)(bm * BMT + inst * 16 + lr) * K + k0 + l4 * 8, &As[inst * 512]);
        }
#pragma unroll
        for (int i = 0; i < 2; ++i) {
            int inst = wave + 4 * i;
            glds16(Bw + (size_t)(bn * 128 + inst * 16 + lr) * K + k0 + l4 * 8, &Bs[inst * 512]);
        }
#else
#pragma unroll
        for (int i = 0; i < AI; ++i) {
            int inst = wave + 4 * i;
            ushort8 a = *(const ushort8*)(A + (size_t)(bm * BMT + inst * 16 + lr) * K + k0 + l4 * 8);
            *(ushort8*)(As + inst * 512 + lane * 8) = a;
        }
#pragma unroll
        for (int i = 0; i < 2; ++i) {
            int inst = wave + 4 * i;
            ushort8 b2 = *(const ushort8*)(Bw + (size_t)(bn * 128 + inst * 16 + lr) * K + k0 + l4 * 8);
            *(ushort8*)(Bs + inst * 512 + lane * 8) = b2;
        }
#endif
        __syncthreads();   // vmcnt drain: LDS populated

        short8 afr[MI], bfr[4];
#pragma unroll
        for (int i = 0; i < MI; ++i) {
            int row = warp_m * (BMT / 2) + i * 16 + r16;
            afr[i] = *(const short8*)(As + row * 32 + quad * 8);
        }
#pragma unroll
        for (int j = 0; j < 4; ++j) {
            int row = warp_n * 64 + j * 16 + r16;
            bfr[j] = *(const short8*)(Bs + row * 32 + quad * 8);
        }
#pragma unroll
        for (int i = 0; i < MI; ++i)
#pragma unroll
            for (int j = 0; j < 4; ++j)
                acc[i][j] = __builtin_amdgcn_mfma_f32_16x16x32_bf16(afr[i], bfr[j], acc[i][j], 0, 0, 0);
    }

    const float* bp = (bn * 128 >= bsplit) ? (bias2 - bsplit) : bias;
#pragma unroll
    for (int j = 0; j < 4; ++j) {
        int gcol = bn * 128 + warp_n * 64 + j * 16 + r16;
        float bv = bp[gcol];
#pragma unroll
        for (int i = 0; i < MI; ++i) {
#pragma unroll
            for (int r = 0; r < 4; ++r) {
                int grow = bm * BMT + warp_m * (BMT / 2) + i * 16 + quad * 4 + r;
                float v = acc[i][j][r] + bv;
                size_t idx = (size_t)grow * N + gcol;
                if (ADD_SKIP) v += skip[idx];
                if (OUT_BF16)
                    ((unsigned short*)Cout)[idx] = f2bf(v);
                else
                    ((float*)Cout)[idx] = v;
            }
        }
    }
}

// ---------------- MFMA flash attention, paired q-tiles ----------------
// grid (S/128, H, B): block handles q-tiles qtA=bx and qtB=31-bx (constant
// total work), sharing K/V staging. 4 waves; wave w owns rows w*16..+16 of
// BOTH tiles. Per k-tile: S^T = K·Q^T, log2-domain online softmax, P via
// per-wave LDS, O += P·V with V staged transposed.
#define STK 72
#define STV 68
#define STP 72
#define QKVS (3 * Dn)   // fused QKV row stride

__global__ __launch_bounds__(256, 4) void attn_kernel(const unsigned short* __restrict__ QKV,
                                                      const int* __restrict__ lens,
                                                      unsigned short* __restrict__ Ctx) {
    const int h = blockIdx.y, b = blockIdx.z;
    const int qtA = blockIdx.x;                 // 0..15
    const int qtB = (Sn / 64 - 1) - qtA;        // 31..16
    const int tid = threadIdx.x;
    const int wave = tid >> 6, lane = tid & 63;
    const int quad = lane >> 4, c = lane & 15;
    const int len = lens[b];
    const int lt = (len - 1) >> 6;
    const int ktendA = min(qtA, lt);
    const int ktendB = min(qtB, lt);            // >= ktendA always
    const int qwA = qtA * 64 + wave * 16;
    const int qwB = qtB * 64 + wave * 16;
    const int myqA = qwA + c, myqB = qwB + c;

    __shared__ unsigned short Ks[64 * STK];
    __shared__ unsigned short Vt[64 * STV];
    __shared__ unsigned short Ps[4][16 * STP];

    // Q fragments for both chunks (B-operand layout)
    short8 qfA[2], qfB[2];
    {
        const unsigned short* qa = QKV + (size_t)(b * Sn + qwA + c) * QKVS + h * 64 + quad * 8;
        qfA[0] = *(const short8*)(qa);
        qfA[1] = *(const short8*)(qa + 32);
        const unsigned short* qb = QKV + (size_t)(b * Sn + qwB + c) * QKVS + h * 64 + quad * 8;
        qfB[0] = *(const short8*)(qb);
        qfB[1] = *(const short8*)(qb + 32);
    }

    f32x4 accA[4], accB[4];
#pragma unroll
    for (int j = 0; j < 4; j++) {
        accA[j] = (f32x4){0.f, 0.f, 0.f, 0.f};
        accB[j] = (f32x4){0.f, 0.f, 0.f, 0.f};
    }
    float mA = -1e30f, lA = 0.f, mB = -1e30f, lB = 0.f;

    // staging thread mappings
    const int krow = tid >> 2, dp = tid & 3;   // K: row krow, 16-col chunk dp
    const int kg = tid >> 4, dg = tid & 15;    // V: k rows kg*4..+3, dh cols dg*4..+3
    const unsigned short* kbase = QKV + (size_t)(b * Sn) * QKVS + Dn + h * 64;        // K cols
    const unsigned short* vbase = QKV + (size_t)(b * Sn) * QKVS + 2 * Dn + h * 64;    // V cols

    // prologue: prefetch tile 0
    ushort8 kr0, kr1;
    ushort4v vr0, vr1, vr2, vr3;
    {
        const unsigned short* kp2 = kbase + (size_t)krow * QKVS + dp * 16;
        kr0 = *(const ushort8*)(kp2);
        kr1 = *(const ushort8*)(kp2 + 8);
        const unsigned short* vp2 = vbase + (size_t)(kg * 4) * QKVS + dg * 4;
        vr0 = *(const ushort4v*)(vp2);
        vr1 = *(const ushort4v*)(vp2 + QKVS);
        vr2 = *(const ushort4v*)(vp2 + 2 * QKVS);
        vr3 = *(const ushort4v*)(vp2 + 3 * QKVS);
    }

    const float C2 = 0.18033688011112042f;   // (1/sqrt(64)) * log2(e)

    // per-chunk compute: S^T -> softmax -> P -> O += P·V
    auto process = [&](int kt, const short8* qf, f32x4* acc_o, float& m_run, float& l_run,
                       int qw, int myq) {
        f32x4 sacc[4];
#pragma unroll
        for (int mt = 0; mt < 4; ++mt) sacc[mt] = (f32x4){0.f, 0.f, 0.f, 0.f};
#pragma unroll
        for (int mt = 0; mt < 4; ++mt) {
            short8 kf0 = *(const short8*)(&Ks[(mt * 16 + c) * STK + quad * 8]);
            short8 kf1 = *(const short8*)(&Ks[(mt * 16 + c) * STK + 32 + quad * 8]);
            sacc[mt] = __builtin_amdgcn_mfma_f32_16x16x32_bf16(kf0, qf[0], sacc[mt], 0, 0, 0);
            sacc[mt] = __builtin_amdgcn_mfma_f32_16x16x32_bf16(kf1, qf[1], sacc[mt], 0, 0, 0);
        }

        const int kb = kt * 64;
        const bool full = (kb + 63 <= qw) && (kb + 64 <= len);
        float sv[16];
        float mx = -1e30f;
        if (full) {
#pragma unroll
            for (int e = 0; e < 16; ++e) {
                float v = sacc[e >> 2][e & 3];
                sv[e] = v;
                mx = fmaxf(mx, v);
            }
        } else {
#pragma unroll
            for (int mt = 0; mt < 4; ++mt) {
#pragma unroll
                for (int r = 0; r < 4; ++r) {
                    int kpos = kb + mt * 16 + quad * 4 + r;
                    bool valid = (kpos <= myq) && (kpos < len);
                    float v = valid ? sacc[mt][r] : -1e30f;
                    sv[mt * 4 + r] = v;
                    mx = fmaxf(mx, v);
                }
            }
        }
        mx = fmaxf(mx, __shfl_xor(mx, 16));
        mx = fmaxf(mx, __shfl_xor(mx, 32));
        float mnew = fmaxf(m_run, mx * C2);   // log2 domain
        float alpha = fast_exp2(m_run - mnew);
        m_run = mnew;
        l_run *= alpha;

        float ar_[4];
#pragma unroll
        for (int r = 0; r < 4; ++r) ar_[r] = __shfl(alpha, quad * 4 + r);
#pragma unroll
        for (int j = 0; j < 4; ++j)
#pragma unroll
            for (int r = 0; r < 4; ++r) acc_o[j][r] *= ar_[r];

#pragma unroll
        for (int mt = 0; mt < 4; ++mt) {
            float p0 = fast_exp2(__builtin_fmaf(sv[mt * 4 + 0], C2, -mnew));
            float p1 = fast_exp2(__builtin_fmaf(sv[mt * 4 + 1], C2, -mnew));
            float p2 = fast_exp2(__builtin_fmaf(sv[mt * 4 + 2], C2, -mnew));
            float p3 = fast_exp2(__builtin_fmaf(sv[mt * 4 + 3], C2, -mnew));
            l_run += (p0 + p1) + (p2 + p3);
            ushort4v pw;
            pw.x = f2bf_t(p0); pw.y = f2bf_t(p1); pw.z = f2bf_t(p2); pw.w = f2bf_t(p3);
            *(ushort4v*)(&Ps[wave][c * STP + mt * 16 + quad * 4]) = pw;
        }
        // same-wave LDS ordering: DS ops in-order, no barrier needed

#pragma unroll
        for (int ks = 0; ks < 2; ++ks) {
            short8 pf = *(const short8*)(&Ps[wave][c * STP + ks * 32 + quad * 8]);
#pragma unroll
            for (int j = 0; j < 4; ++j) {
                const unsigned short* vb2 = &Vt[(j * 16 + c) * STV + ks * 32 + quad * 8];
                short4v a0 = *(const short4v*)(vb2);
                short4v a1 = *(const short4v*)(vb2 + 4);
                short8 vf = __builtin_shufflevector(a0, a1, 0, 1, 2, 3, 4, 5, 6, 7);
                acc_o[j] = __builtin_amdgcn_mfma_f32_16x16x32_bf16(pf, vf, acc_o[j], 0, 0, 0);
            }
        }
    };

    for (int kt = 0; kt <= ktendB; ++kt) {
        __syncthreads();   // prior iteration's LDS readers done
        // write prefetched tile to LDS
        *(ushort8*)(&Ks[krow * STK + dp * 16]) = kr0;
        *(ushort8*)(&Ks[krow * STK + dp * 16 + 8]) = kr1;
#pragma unroll
        for (int w = 0; w < 4; ++w) {
            ushort4v t;
            t.x = vr0[w]; t.y = vr1[w]; t.z = vr2[w]; t.w = vr3[w];
            *(ushort4v*)(&Vt[(dg * 4 + w) * STV + kg * 4]) = t;
        }
        __syncthreads();

        // issue next tile's global loads (overlap with compute below)
        if (kt < ktendB) {
            const unsigned short* kp2 = kbase + (size_t)((kt + 1) * 64 + krow) * QKVS + dp * 16;
            kr0 = *(const ushort8*)(kp2);
            kr1 = *(const ushort8*)(kp2 + 8);
            const unsigned short* vp2 = vbase + (size_t)((kt + 1) * 64 + kg * 4) * QKVS + dg * 4;
            vr0 = *(const ushort4v*)(vp2);
            vr1 = *(const ushort4v*)(vp2 + QKVS);
            vr2 = *(const ushort4v*)(vp2 + 2 * QKVS);
            vr3 = *(const ushort4v*)(vp2 + 3 * QKVS);
        }

        if (kt <= ktendA)
            process(kt, qfA, accA, mA, lA, qwA, myqA);
        process(kt, qfB, accB, mB, lB, qwB, myqB);
    }

    // ---- finalize both chunks ----
    auto finalize = [&](f32x4* acc_o, float l_run, int qw) {
        l_run += __shfl_xor(l_run, 16);
        l_run += __shfl_xor(l_run, 32);
        float li[4];
#pragma unroll
        for (int r = 0; r < 4; ++r) {
            float lv = __shfl(l_run, quad * 4 + r);
            li[r] = 1.0f / lv;
        }
#pragma unroll
        for (int r = 0; r < 4; ++r) {
            unsigned short* cp = Ctx + ((size_t)(b * Sn + qw + quad * 4 + r)) * Dn + h * 64 + c;
#pragma unroll
            for (int j = 0; j < 4; ++j) {
                cp[j * 16] = f2bf(acc_o[j][r] * li[r]);
            }
        }
    };
    finalize(accA, lA, qwA);
    finalize(accB, lB, qwB);
}

// ---------------- launcher ----------------
extern "C" void kernel_launch(void* const* d_in, const int* in_sizes, int n_in,
                              void* d_out, int out_size, void* d_ws, size_t ws_size,
                              hipStream_t stream) {
    const float* x = (const float*)d_in[0];
    const int* lens = (const int*)d_in[1];
    const float* Wq = (const float*)d_in[2];
    const float* bq = (const float*)d_in[3];
    const float* Wkv = (const float*)d_in[4];
    const float* bkv = (const float*)d_in[5];
    const float* Wo = (const float*)d_in[6];
    const float* bo = (const float*)d_in[7];
    const float* ln_g = (const float*)d_in[8];
    const float* ln_b = (const float*)d_in[9];
    float* out = (float*)d_out;

    char* ws = (char*)d_ws;
    unsigned short* xn_bf = (unsigned short*)ws;                                // 16 MB
    unsigned short* wq_bf = (unsigned short*)(ws + (size_t)16 * 1024 * 1024);   // 2 MB  (Wq | Wkv contiguous -> N=3072 weight)
    unsigned short* wkv_bf = (unsigned short*)(ws + (size_t)18 * 1024 * 1024);  // 4 MB
    unsigned short* wo_bf = (unsigned short*)(ws + (size_t)22 * 1024 * 1024);   // 2 MB
    unsigned short* qkv_bf = (unsigned short*)(ws + (size_t)24 * 1024 * 1024);  // 48 MB (M x 3072)
    unsigned short* ctx_bf = (unsigned short*)(ws + (size_t)72 * 1024 * 1024);  // 16 MB

    // prep: LN (8192 blocks) + weight casts (4096 blocks)
    prep_kernel<<<Mn + 4096, 256, 0, stream>>>(x, ln_g, ln_b, xn_bf,
                                               Wq, Wkv, Wo, wq_bf, wkv_bf, wo_bf);

    // fused QKV = xn @ [Wq;Wkv]^T + [bq;bkv]  (bf16 out, M x 3072)
    {
        dim3 grid(Mn / 128, 3 * Dn / 128);
        gemm_bt<128, false, true><<<grid, 256, 0, stream>>>(xn_bf, wq_bf, bq, bkv, Dn, nullptr,
                                                            (void*)qkv_bf, Mn, 3 * Dn, Dn);
    }
    // attention -> ctx bf16
    {
        dim3 grid(Sn / 128, Hn, Bn);
        attn_kernel<<<grid, 256, 0, stream>>>(qkv_bf, lens, ctx_bf);
    }
    // out = ctx @ Wo^T + bo + x   (fp32 out); 64-row tiles -> 1024 blocks = 4/CU
    {
        dim3 grid(Mn / 64, Dn / 128);
        gemm_bt<64, true, false><<<grid, 256, 0, stream>>>(ctx_bf, wo_bf, bo, bo, Dn, x,
                                                           (void*)out, Mn, Dn, Dn);
    }
}